// Round 1
// baseline (429.077 us; speedup 1.0000x reference)
//
#include <hip/hip_runtime.h>
#include <stdint.h>
#include <stddef.h>

typedef short short8 __attribute__((ext_vector_type(8)));
typedef float f32x4 __attribute__((ext_vector_type(4)));

#define MFMA16(a, b, c) __builtin_amdgcn_mfma_f32_16x16x32_bf16(a, b, c, 0, 0, 0)

static constexpr int B = 4, C = 256, G = 4, CG = 64, N = 4096;

__device__ __forceinline__ unsigned short f2bf(float f) {
  unsigned int u = __builtin_bit_cast(unsigned int, f);
  u += 0x7FFFu + ((u >> 16) & 1u);
  return (unsigned short)(u >> 16);
}

// ---------------------------------------------------------------------------
// Kernel 1: grouped 1x1 convs -> qT [b][n][c] (scaled by 1/16), kT [b][n][c],
// v [b][c][n], all bf16 (stored as u16).
// grid: (ntile=16, b*4+g=16, which=3); block 256.
// ---------------------------------------------------------------------------
__global__ __launch_bounds__(256) void qkv_kernel(
    const float* __restrict__ rgb, const float* __restrict__ ir,
    const float* __restrict__ wq, const float* __restrict__ bq,
    const float* __restrict__ wk, const float* __restrict__ bk,
    const float* __restrict__ wvv, const float* __restrict__ bvv,
    unsigned short* __restrict__ qT, unsigned short* __restrict__ kT,
    unsigned short* __restrict__ vN) {
  __shared__ unsigned char xTs[256 * 144];  // [n_local 256][cin 64 pad->72] bf16
  __shared__ unsigned char wls[64 * 144];   // [cout 64][cin 64 pad->72] bf16

  const int tid = threadIdx.x;
  const int which = blockIdx.z;           // 0=q 1=k 2=v
  const int bg = blockIdx.y;
  const int b = bg >> 2, g = bg & 3;
  const int n0 = blockIdx.x * 256;

  const float* x = (which == 0) ? rgb : ir;
  const float* w = (which == 0) ? wq : (which == 1 ? wk : wvv);
  const float* bias = (which == 0) ? bq : (which == 1 ? bk : bvv);

  // ---- stage xT (transpose f32 [cin][n] -> bf16 LDS [n_local][cin]) ----
  {
    const int p = tid & 31;             // cin pair index (cin = 2p, 2p+1)
    const int jseg = (tid >> 5) * 32;   // 8 segments of 32 n's
    const float* r0 = x + ((size_t)(b * C + g * CG + 2 * p) * N + n0 + jseg);
    const float* r1 = r0 + N;
#pragma unroll
    for (int ii = 0; ii < 8; ii++) {
      f32x4 a = *(const f32x4*)(r0 + 4 * ii);
      f32x4 c2 = *(const f32x4*)(r1 + 4 * ii);
#pragma unroll
      for (int e = 0; e < 4; e++) {
        unsigned int pk =
            (unsigned int)f2bf(a[e]) | ((unsigned int)f2bf(c2[e]) << 16);
        *(unsigned int*)(xTs + (size_t)(jseg + 4 * ii + e) * 144 + 4 * p) = pk;
      }
    }
  }
  // ---- stage w (f32 [cout][cin] -> bf16 LDS [cout][cin]) ----
  {
    const int o = tid >> 2;
    const int cs = (tid & 3) * 16;
    const float* wr = w + (size_t)g * CG * CG + (size_t)o * CG + cs;
#pragma unroll
    for (int i = 0; i < 8; i++) {
      unsigned int pk = (unsigned int)f2bf(wr[2 * i]) |
                        ((unsigned int)f2bf(wr[2 * i + 1]) << 16);
      *(unsigned int*)(wls + (size_t)o * 144 + (cs + 2 * i) * 2) = pk;
    }
  }
  __syncthreads();

  const int wv_ = tid >> 6, lane = tid & 63, l15 = lane & 15, g16 = lane >> 4;
  const f32x4 zero4 = {0.f, 0.f, 0.f, 0.f};
  f32x4 acc[4][4];
#pragma unroll
  for (int i = 0; i < 4; i++)
#pragma unroll
    for (int j = 0; j < 4; j++) acc[i][j] = zero4;

  if (which < 2) {
    // C = out^T [n 256][cout 64]; wave handles n-rows wv_*64..+63
#pragma unroll
    for (int kk = 0; kk < 2; kk++) {
      short8 af[4], bfr[4];
#pragma unroll
      for (int mt = 0; mt < 4; mt++)
        af[mt] = *(const short8*)(xTs +
                                  (size_t)(wv_ * 64 + mt * 16 + l15) * 144 +
                                  (kk * 32 + 8 * g16) * 2);
#pragma unroll
      for (int nt = 0; nt < 4; nt++)
        bfr[nt] = *(const short8*)(wls + (size_t)(nt * 16 + l15) * 144 +
                                   (kk * 32 + 8 * g16) * 2);
#pragma unroll
      for (int mt = 0; mt < 4; mt++)
#pragma unroll
        for (int nt = 0; nt < 4; nt++)
          acc[mt][nt] = MFMA16(af[mt], bfr[nt], acc[mt][nt]);
    }
    unsigned short* out = (which == 0) ? qT : kT;
    const float qs = (which == 0) ? 0.0625f : 1.0f;  // fold c^-0.5 into q
#pragma unroll
    for (int mt = 0; mt < 4; mt++)
#pragma unroll
      for (int nt = 0; nt < 4; nt++)
#pragma unroll
        for (int r = 0; r < 4; r++) {
          int nl = wv_ * 64 + mt * 16 + 4 * g16 + r;
          int co = nt * 16 + l15;
          float val = (acc[mt][nt][r] + bias[g * CG + co]) * qs;
          out[(size_t)(b * N + n0 + nl) * C + g * CG + co] = f2bf(val);
        }
  } else {
    // C = out [cout 64][n 256]; wave handles n-cols wv_*64..+63
#pragma unroll
    for (int kk = 0; kk < 2; kk++) {
      short8 af[4], bfr[4];
#pragma unroll
      for (int mt = 0; mt < 4; mt++)
        af[mt] = *(const short8*)(wls + (size_t)(mt * 16 + l15) * 144 +
                                  (kk * 32 + 8 * g16) * 2);
#pragma unroll
      for (int nt = 0; nt < 4; nt++)
        bfr[nt] = *(const short8*)(xTs +
                                   (size_t)(wv_ * 64 + nt * 16 + l15) * 144 +
                                   (kk * 32 + 8 * g16) * 2);
#pragma unroll
      for (int mt = 0; mt < 4; mt++)
#pragma unroll
        for (int nt = 0; nt < 4; nt++)
          acc[mt][nt] = MFMA16(af[mt], bfr[nt], acc[mt][nt]);
    }
#pragma unroll
    for (int mt = 0; mt < 4; mt++)
#pragma unroll
      for (int nt = 0; nt < 4; nt++)
#pragma unroll
        for (int r = 0; r < 4; r++) {
          int co = mt * 16 + 4 * g16 + r;
          int nl = wv_ * 64 + nt * 16 + l15;
          float val = acc[mt][nt][r] + bias[g * CG + co];
          vN[(size_t)(b * C + g * CG + co) * N + n0 + nl] = f2bf(val);
        }
  }
}

// ---------------------------------------------------------------------------
// Kernel 2: flash attention. zT[b][n][c] = softmax(qT kT^T) @ v^T, bf16 out.
// grid: (qtile=64, b=4); block 256 (4 waves x 16 query rows). j-step 32.
// ---------------------------------------------------------------------------
__global__ __launch_bounds__(256) void attn_kernel(
    const unsigned short* __restrict__ qT, const unsigned short* __restrict__ kT,
    const unsigned short* __restrict__ vN, unsigned short* __restrict__ zT) {
  __shared__ unsigned char Kl[32 * 512];   // [j 32][c 256] bf16, XOR-swizzled 16B chunks
  __shared__ unsigned char Vl[256 * 80];   // [c 256][j 32 pad->40] bf16 (80B rows)
  __shared__ unsigned char Pl[4][16 * 80]; // per-wave [i 16][j 32 pad->40] bf16

  const int tid = threadIdx.x;
  const int b = blockIdx.y;
  const int q0 = blockIdx.x * 64;
  const int wv_ = tid >> 6, lane = tid & 63, l15 = lane & 15, g16 = lane >> 4;
  const f32x4 zero4 = {0.f, 0.f, 0.f, 0.f};

  // Q fragments (held in registers for the whole kernel)
  short8 qf[8];
  const int qi = q0 + wv_ * 16 + l15;
#pragma unroll
  for (int kk = 0; kk < 8; kk++)
    qf[kk] = *(const short8*)(qT + (size_t)(b * N + qi) * C + kk * 32 + 8 * g16);

  f32x4 zacc[16];
#pragma unroll
  for (int i = 0; i < 16; i++) zacc[i] = zero4;
  float m[4] = {-1e30f, -1e30f, -1e30f, -1e30f};
  float ls[4] = {0.f, 0.f, 0.f, 0.f};

  for (int jt = 0; jt < N / 32; jt++) {
    const int j0 = jt * 32;
    // ---- stage K tile: [32 j][256 c] ----
    {
      const int jr = tid >> 3, cs = (tid & 7) * 32;
      const unsigned short* src = kT + (size_t)(b * N + j0 + jr) * C + cs;
#pragma unroll
      for (int ii = 0; ii < 4; ii++) {
        short8 d = *(const short8*)(src + ii * 8);
        int byte = jr * 512 + (cs + ii * 8) * 2;
        *(short8*)(Kl + (byte ^ ((jr & 7) << 4))) = d;
      }
    }
    // ---- stage V tile: [256 c][32 j] ----
    {
      const unsigned short* src = vN + (size_t)(b * C + tid) * N + j0;
#pragma unroll
      for (int ii = 0; ii < 4; ii++) {
        short8 d = *(const short8*)(src + ii * 8);
        *(short8*)(Vl + tid * 80 + ii * 16) = d;
      }
    }
    __syncthreads();

    // ---- S = Q K^T (two 16-col subtiles), K-reduction over c=256 ----
    f32x4 cs0 = zero4, cs1 = zero4;
    const int jA = l15, jB = 16 + l15;
    const int kofsA = ((jA * 512) ^ ((jA & 7) << 4));
    const int kofsB = ((jB * 512) ^ ((jB & 7) << 4));
#pragma unroll
    for (int kk = 0; kk < 8; kk++) {
      short8 kfa = *(const short8*)(Kl + kofsA + (kk * 32 + 8 * g16) * 2);
      short8 kfb = *(const short8*)(Kl + kofsB + (kk * 32 + 8 * g16) * 2);
      cs0 = MFMA16(qf[kk], kfa, cs0);
      cs1 = MFMA16(qf[kk], kfb, cs1);
    }

    // ---- online softmax (rows live in C-frag layout: row = 4*g16 + r) ----
    float rm[4], rs[4], al[4];
#pragma unroll
    for (int r = 0; r < 4; r++) rm[r] = fmaxf(cs0[r], cs1[r]);
#pragma unroll
    for (int off = 1; off < 16; off <<= 1)
#pragma unroll
      for (int r = 0; r < 4; r++) rm[r] = fmaxf(rm[r], __shfl_xor(rm[r], off));
#pragma unroll
    for (int r = 0; r < 4; r++) {
      float mn = fmaxf(m[r], rm[r]);
      al[r] = __expf(m[r] - mn);
      m[r] = mn;
      float p0 = __expf(cs0[r] - mn);
      float p1 = __expf(cs1[r] - mn);
      cs0[r] = p0;
      cs1[r] = p1;
      rs[r] = p0 + p1;
    }
#pragma unroll
    for (int off = 1; off < 16; off <<= 1)
#pragma unroll
      for (int r = 0; r < 4; r++) rs[r] += __shfl_xor(rs[r], off);
#pragma unroll
    for (int r = 0; r < 4; r++) ls[r] = ls[r] * al[r] + rs[r];
#pragma unroll
    for (int i = 0; i < 16; i++)
#pragma unroll
      for (int r = 0; r < 4; r++) zacc[i][r] *= al[r];

    // ---- P -> LDS (transpose C-layout -> A-layout), then PV ----
    unsigned char* P = Pl[wv_];
#pragma unroll
    for (int r = 0; r < 4; r++) {
      int il = 4 * g16 + r;
      *(unsigned short*)(P + il * 80 + l15 * 2) = f2bf(cs0[r]);
      *(unsigned short*)(P + il * 80 + (16 + l15) * 2) = f2bf(cs1[r]);
    }
    short8 paf = *(const short8*)(P + l15 * 80 + (8 * g16) * 2);
#pragma unroll
    for (int nt = 0; nt < 16; nt++) {
      int c = nt * 16 + l15;
      short8 vfr = *(const short8*)(Vl + c * 80 + 16 * g16);
      zacc[nt] = MFMA16(paf, vfr, zacc[nt]);
    }
    __syncthreads();
  }

  // ---- epilogue: z / l, store zT bf16 ----
#pragma unroll
  for (int r = 0; r < 4; r++) {
    float inv = 1.0f / ls[r];
    int i = q0 + wv_ * 16 + 4 * g16 + r;
#pragma unroll
    for (int nt = 0; nt < 16; nt++) {
      zT[(size_t)(b * N + i) * C + nt * 16 + l15] = f2bf(zacc[nt][r] * inv);
    }
  }
}

// ---------------------------------------------------------------------------
// Kernel 3: y = w4 @ z + b4 -> BN(eval) -> mish -> + rgb. f32 out.
// grid: (ntile=64, b=4); block 256 (4 waves; wave owns 64 cout x 64 n).
// ---------------------------------------------------------------------------
__global__ __launch_bounds__(256) void out_kernel(
    const unsigned short* __restrict__ zT, const float* __restrict__ w4,
    const float* __restrict__ b4, const float* __restrict__ gamma,
    const float* __restrict__ beta, const float* __restrict__ rmean,
    const float* __restrict__ rvar, const float* __restrict__ rgb,
    float* __restrict__ out) {
  const int tid = threadIdx.x;
  const int b = blockIdx.y;
  const int n0 = blockIdx.x * 64;
  const int wv_ = tid >> 6, lane = tid & 63, l15 = lane & 15, g16 = lane >> 4;
  const f32x4 zero4 = {0.f, 0.f, 0.f, 0.f};

  f32x4 acc[4][4];  // [mt over cout][nt over n]
#pragma unroll
  for (int i = 0; i < 4; i++)
#pragma unroll
    for (int j = 0; j < 4; j++) acc[i][j] = zero4;

#pragma unroll
  for (int kk = 0; kk < 8; kk++) {
    short8 bfr[4];
#pragma unroll
    for (int nt = 0; nt < 4; nt++)
      bfr[nt] = *(const short8*)(zT + (size_t)(b * N + n0 + nt * 16 + l15) * C +
                                 kk * 32 + 8 * g16);
    short8 afr[4];
#pragma unroll
    for (int mt = 0; mt < 4; mt++) {
      const float* wr =
          w4 + (size_t)(wv_ * 64 + mt * 16 + l15) * C + kk * 32 + 8 * g16;
      f32x4 wa = *(const f32x4*)(wr);
      f32x4 wb = *(const f32x4*)(wr + 4);
      short8 t;
#pragma unroll
      for (int e = 0; e < 4; e++) {
        t[e] = (short)f2bf(wa[e]);
        t[4 + e] = (short)f2bf(wb[e]);
      }
      afr[mt] = t;
    }
#pragma unroll
    for (int mt = 0; mt < 4; mt++)
#pragma unroll
      for (int nt = 0; nt < 4; nt++)
        acc[mt][nt] = MFMA16(afr[mt], bfr[nt], acc[mt][nt]);
  }

#pragma unroll
  for (int mt = 0; mt < 4; mt++)
#pragma unroll
    for (int r = 0; r < 4; r++) {
      int co = wv_ * 64 + mt * 16 + 4 * g16 + r;
      float bb = b4[co];
      float inv = gamma[co] * rsqrtf(rvar[co] + 1e-5f);
      float sh = beta[co] - rmean[co] * inv;
#pragma unroll
      for (int nt = 0; nt < 4; nt++) {
        int n = n0 + nt * 16 + l15;
        size_t idx = (size_t)(b * C + co) * N + n;
        float yv = acc[mt][nt][r] + bb;
        float tv = yv * inv + sh;
        // mish(t) = t * tanh(softplus(t)) = t * (u^2-1)/(u^2+1), u = 1+e^t
        float s = __expf(fminf(tv, 40.f));
        float u = 1.f + s;
        float u2 = u * u;
        float mish = tv * ((u2 - 1.f) / (u2 + 1.f));
        out[idx] = rgb[idx] + mish;
      }
    }
}

// ---------------------------------------------------------------------------
extern "C" void kernel_launch(void* const* d_in, const int* in_sizes, int n_in,
                              void* d_out, int out_size, void* d_ws,
                              size_t ws_size, hipStream_t stream) {
  const float* rgb = (const float*)d_in[0];
  const float* ir = (const float*)d_in[1];
  const float* wq = (const float*)d_in[2];
  const float* bq = (const float*)d_in[3];
  const float* wk = (const float*)d_in[4];
  const float* bk = (const float*)d_in[5];
  const float* wvv = (const float*)d_in[6];
  const float* bvv = (const float*)d_in[7];
  const float* w4 = (const float*)d_in[8];
  const float* b4 = (const float*)d_in[9];
  const float* gamma = (const float*)d_in[10];
  const float* beta = (const float*)d_in[11];
  const float* rmean = (const float*)d_in[12];
  const float* rvar = (const float*)d_in[13];

  unsigned short* qT = (unsigned short*)d_ws;          // [B][N][C] bf16
  unsigned short* kT = qT + (size_t)B * N * C;         // [B][N][C] bf16
  unsigned short* vN = kT + (size_t)B * N * C;         // [B][C][N] bf16
  unsigned short* zT = vN + (size_t)B * N * C;         // [B][N][C] bf16

  qkv_kernel<<<dim3(16, 16, 3), 256, 0, stream>>>(rgb, ir, wq, bq, wk, bk, wvv,
                                                  bvv, qT, kT, vN);
  attn_kernel<<<dim3(64, 4), 256, 0, stream>>>(qT, kT, vN, zT);
  out_kernel<<<dim3(64, 4), 256, 0, stream>>>(zT, w4, b4, gamma, beta, rmean,
                                              rvar, rgb, (float*)d_out);
}

// Round 2
// 318.169 us; speedup vs baseline: 1.3486x; 1.3486x over previous
//
#include <hip/hip_runtime.h>
#include <stdint.h>
#include <stddef.h>

typedef short short8 __attribute__((ext_vector_type(8)));
typedef short short4v __attribute__((ext_vector_type(4)));
typedef float f32x4 __attribute__((ext_vector_type(4)));

#define MFMA16(a, b, c) __builtin_amdgcn_mfma_f32_16x16x32_bf16(a, b, c, 0, 0, 0)

static constexpr int B = 4, C = 256, CG = 64, N = 4096;
static constexpr int NH = N / 2;        // keys per wavegroup (split-K 2)
static constexpr int NSTEPS = NH / 32;  // 64

__device__ __forceinline__ unsigned short f2bf(float f) {
  unsigned int u = __builtin_bit_cast(unsigned int, f);
  u += 0x7FFFu + ((u >> 16) & 1u);
  return (unsigned short)(u >> 16);
}

// ---------------------------------------------------------------------------
// Kernel 1: grouped 1x1 convs -> qT [b][n][c] (scaled by c^-0.5), kT [b][n][c],
// v [b][c][n], all bf16 (stored as u16).
// grid: (ntile=16, b*4+g=16, which=3); block 256.
// ---------------------------------------------------------------------------
__global__ __launch_bounds__(256) void qkv_kernel(
    const float* __restrict__ rgb, const float* __restrict__ ir,
    const float* __restrict__ wq, const float* __restrict__ bq,
    const float* __restrict__ wk, const float* __restrict__ bk,
    const float* __restrict__ wvv, const float* __restrict__ bvv,
    unsigned short* __restrict__ qT, unsigned short* __restrict__ kT,
    unsigned short* __restrict__ vN) {
  __shared__ unsigned char xTs[256 * 144];  // [n_local 256][cin 64 pad->72] bf16
  __shared__ unsigned char wls[64 * 144];   // [cout 64][cin 64 pad->72] bf16

  const int tid = threadIdx.x;
  const int which = blockIdx.z;           // 0=q 1=k 2=v
  const int bg = blockIdx.y;
  const int b = bg >> 2, g = bg & 3;
  const int n0 = blockIdx.x * 256;

  const float* x = (which == 0) ? rgb : ir;
  const float* w = (which == 0) ? wq : (which == 1 ? wk : wvv);
  const float* bias = (which == 0) ? bq : (which == 1 ? bk : bvv);

  // ---- stage xT (transpose f32 [cin][n] -> bf16 LDS [n_local][cin]) ----
  {
    const int p = tid & 31;             // cin pair index (cin = 2p, 2p+1)
    const int jseg = (tid >> 5) * 32;   // 8 segments of 32 n's
    const float* r0 = x + ((size_t)(b * C + g * CG + 2 * p) * N + n0 + jseg);
    const float* r1 = r0 + N;
#pragma unroll
    for (int ii = 0; ii < 8; ii++) {
      f32x4 a = *(const f32x4*)(r0 + 4 * ii);
      f32x4 c2 = *(const f32x4*)(r1 + 4 * ii);
#pragma unroll
      for (int e = 0; e < 4; e++) {
        unsigned int pk =
            (unsigned int)f2bf(a[e]) | ((unsigned int)f2bf(c2[e]) << 16);
        *(unsigned int*)(xTs + (size_t)(jseg + 4 * ii + e) * 144 + 4 * p) = pk;
      }
    }
  }
  // ---- stage w (f32 [cout][cin] -> bf16 LDS [cout][cin]) ----
  {
    const int o = tid >> 2;
    const int cs = (tid & 3) * 16;
    const float* wr = w + (size_t)g * CG * CG + (size_t)o * CG + cs;
#pragma unroll
    for (int i = 0; i < 8; i++) {
      unsigned int pk = (unsigned int)f2bf(wr[2 * i]) |
                        ((unsigned int)f2bf(wr[2 * i + 1]) << 16);
      *(unsigned int*)(wls + (size_t)o * 144 + (cs + 2 * i) * 2) = pk;
    }
  }
  __syncthreads();

  const int wv_ = tid >> 6, lane = tid & 63, l15 = lane & 15, g16 = lane >> 4;
  const f32x4 zero4 = {0.f, 0.f, 0.f, 0.f};
  f32x4 acc[4][4];
#pragma unroll
  for (int i = 0; i < 4; i++)
#pragma unroll
    for (int j = 0; j < 4; j++) acc[i][j] = zero4;

  if (which < 2) {
    // C = out^T [n 256][cout 64]; wave handles n-rows wv_*64..+63
#pragma unroll
    for (int kk = 0; kk < 2; kk++) {
      short8 af[4], bfr[4];
#pragma unroll
      for (int mt = 0; mt < 4; mt++)
        af[mt] = *(const short8*)(xTs +
                                  (size_t)(wv_ * 64 + mt * 16 + l15) * 144 +
                                  (kk * 32 + 8 * g16) * 2);
#pragma unroll
      for (int nt = 0; nt < 4; nt++)
        bfr[nt] = *(const short8*)(wls + (size_t)(nt * 16 + l15) * 144 +
                                   (kk * 32 + 8 * g16) * 2);
#pragma unroll
      for (int mt = 0; mt < 4; mt++)
#pragma unroll
        for (int nt = 0; nt < 4; nt++)
          acc[mt][nt] = MFMA16(af[mt], bfr[nt], acc[mt][nt]);
    }
    unsigned short* out = (which == 0) ? qT : kT;
    const float qs = (which == 0) ? 0.0625f : 1.0f;  // fold c^-0.5 into q
#pragma unroll
    for (int mt = 0; mt < 4; mt++)
#pragma unroll
      for (int nt = 0; nt < 4; nt++)
#pragma unroll
        for (int r = 0; r < 4; r++) {
          int nl = wv_ * 64 + mt * 16 + 4 * g16 + r;
          int co = nt * 16 + l15;
          float val = (acc[mt][nt][r] + bias[g * CG + co]) * qs;
          out[(size_t)(b * N + n0 + nl) * C + g * CG + co] = f2bf(val);
        }
  } else {
    // C = out [cout 64][n 256]; wave handles n-cols wv_*64..+63
#pragma unroll
    for (int kk = 0; kk < 2; kk++) {
      short8 af[4], bfr[4];
#pragma unroll
      for (int mt = 0; mt < 4; mt++)
        af[mt] = *(const short8*)(wls + (size_t)(mt * 16 + l15) * 144 +
                                  (kk * 32 + 8 * g16) * 2);
#pragma unroll
      for (int nt = 0; nt < 4; nt++)
        bfr[nt] = *(const short8*)(xTs +
                                   (size_t)(wv_ * 64 + nt * 16 + l15) * 144 +
                                   (kk * 32 + 8 * g16) * 2);
#pragma unroll
      for (int mt = 0; mt < 4; mt++)
#pragma unroll
        for (int nt = 0; nt < 4; nt++)
          acc[mt][nt] = MFMA16(af[mt], bfr[nt], acc[mt][nt]);
    }
#pragma unroll
    for (int mt = 0; mt < 4; mt++)
#pragma unroll
      for (int nt = 0; nt < 4; nt++)
#pragma unroll
        for (int r = 0; r < 4; r++) {
          int co = mt * 16 + 4 * g16 + r;
          int nl = wv_ * 64 + nt * 16 + l15;
          float val = acc[mt][nt][r] + bias[g * CG + co];
          vN[(size_t)(b * C + g * CG + co) * N + n0 + nl] = f2bf(val);
        }
  }
}

// ---------------------------------------------------------------------------
// Kernel 2: flash attention, split-K over 2 wavegroups.
// grid: (qtile=64, b=4); block 512 (8 waves). Each wave: 16 query rows.
// wg0 handles keys [0,2048), wg1 [2048,4096); partials combined via LDS.
// ---------------------------------------------------------------------------
__global__ __launch_bounds__(512) void attn_kernel(
    const unsigned short* __restrict__ qT, const unsigned short* __restrict__ kT,
    const unsigned short* __restrict__ vN, unsigned short* __restrict__ zT) {
  // 0..32KB:   K tiles  [wg][32 rows][512B] (XOR-swizzled 16B chunks)
  // 32..64KB:  V tiles  [wg][256 rows][64B] (chunk-swizzled)
  // 64..74KB:  P bufs   [8 waves][16][80B]
  // overlays:  zbuf f32[4][16][256] on 0..64KB; mlbuf f32[8][16][2] on 64KB+
  __shared__ __align__(16) unsigned char smem[75776];
  unsigned char* Kl = smem;
  unsigned char* Vl = smem + 32768;
  unsigned char* Pl = smem + 65536;
  float* zbuf = (float*)smem;
  float* mlbuf = (float*)(smem + 65536);

  const int tid = threadIdx.x;
  const int b = blockIdx.y;
  const int q0 = blockIdx.x * 64;
  const int wv = tid >> 6, lane = tid & 63;
  const int l15 = lane & 15, g16 = lane >> 4;
  const int wg = wv >> 2, wq = wv & 3;
  const int tw = tid & 255;  // index within wavegroup (staging)
  const f32x4 zero4 = {0.f, 0.f, 0.f, 0.f};

  // ---- Q fragments (registers, whole kernel) ----
  short8 qf[8];
  const int qi = q0 + wq * 16 + l15;
#pragma unroll
  for (int kk = 0; kk < 8; kk++)
    qf[kk] = *(const short8*)(qT + (size_t)(b * N + qi) * C + kk * 32 + 8 * g16);

  f32x4 zacc[16];
#pragma unroll
  for (int i = 0; i < 16; i++) zacc[i] = zero4;
  float m[4] = {-1e30f, -1e30f, -1e30f, -1e30f};
  float ls[4] = {0.f, 0.f, 0.f, 0.f};  // per-lane partial row sums

  // ---- staging geometry ----
  unsigned char* Kw = Kl + wg * 16384;
  unsigned char* Vw = Vl + wg * 16384;
  const int jr = tw >> 3;            // K row 0..31
  const int csK = (tw & 7) * 32;     // K col element base
  const unsigned short* kbase = kT + (size_t)(b * N + wg * NH + jr) * C + csK;
  const unsigned short* vbase = vN + (size_t)(b * C + tw) * N + wg * NH;
  int kofs_w[4], vofs_w[4];
  {
    const int scw = (tw ^ (tw >> 2)) & 3;
#pragma unroll
    for (int ii = 0; ii < 4; ii++) {
      kofs_w[ii] = (jr * 512 + (csK + ii * 8) * 2) ^ ((jr & 7) << 4);
      vofs_w[ii] = tw * 64 + ((ii ^ scw) << 4);
    }
  }
  // ---- read geometry ----
  const int xorw = (l15 & 7) << 4;
  unsigned char* rowA = Kw + l15 * 512;
  unsigned char* rowB = Kw + (16 + l15) * 512;
  const int vsel = ((g16 ^ (l15 ^ (l15 >> 2))) & 3) * 16;
  unsigned char* P = Pl + wv * 1280;

  short8 kreg[4], vreg[4];
  // ---- prologue: stage tile 0 ----
#pragma unroll
  for (int ii = 0; ii < 4; ii++) kreg[ii] = *(const short8*)(kbase + ii * 8);
#pragma unroll
  for (int ii = 0; ii < 4; ii++) vreg[ii] = *(const short8*)(vbase + ii * 8);
#pragma unroll
  for (int ii = 0; ii < 4; ii++) *(short8*)(Kw + kofs_w[ii]) = kreg[ii];
#pragma unroll
  for (int ii = 0; ii < 4; ii++) *(short8*)(Vw + vofs_w[ii]) = vreg[ii];
  __syncthreads();

  for (int jt = 0; jt < NSTEPS; jt++) {
    const bool more = (jt + 1 < NSTEPS);
    // issue next tile's global loads early (latency hides under compute)
    if (more) {
      const unsigned short* kp = kbase + (size_t)(jt + 1) * 32 * C;
      const unsigned short* vp = vbase + (jt + 1) * 32;
#pragma unroll
      for (int ii = 0; ii < 4; ii++) kreg[ii] = *(const short8*)(kp + ii * 8);
#pragma unroll
      for (int ii = 0; ii < 4; ii++) vreg[ii] = *(const short8*)(vp + ii * 8);
    }

    // ---- S = Q K^T over c=256 (two 16-col subtiles) ----
    f32x4 cs0 = zero4, cs1 = zero4;
#pragma unroll
    for (int kk = 0; kk < 8; kk++) {
      short8 kfa = *(const short8*)(rowA + ((kk * 64 + g16 * 16) ^ xorw));
      short8 kfb = *(const short8*)(rowB + ((kk * 64 + g16 * 16) ^ xorw));
      cs0 = MFMA16(qf[kk], kfa, cs0);
      cs1 = MFMA16(qf[kk], kfb, cs1);
    }

    // ---- online softmax with defer-max (THR=8) ----
    float rm[4];
#pragma unroll
    for (int r = 0; r < 4; r++) rm[r] = fmaxf(cs0[r], cs1[r]);
#pragma unroll
    for (int off = 1; off < 16; off <<= 1)
#pragma unroll
      for (int r = 0; r < 4; r++) rm[r] = fmaxf(rm[r], __shfl_xor(rm[r], off));
    float gmx = fmaxf(fmaxf(rm[0] - m[0], rm[1] - m[1]),
                      fmaxf(rm[2] - m[2], rm[3] - m[3]));
    if (__any(gmx > 8.f)) {
#pragma unroll
      for (int r = 0; r < 4; r++) {
        float mn = fmaxf(m[r], rm[r]);
        float al = __expf(m[r] - mn);
        m[r] = mn;
        ls[r] *= al;
#pragma unroll
        for (int nt = 0; nt < 16; nt++) zacc[nt][r] *= al;
      }
    }
    float p0[4], p1[4];
#pragma unroll
    for (int r = 0; r < 4; r++) {
      p0[r] = __expf(cs0[r] - m[r]);
      p1[r] = __expf(cs1[r] - m[r]);
      ls[r] += p0[r] + p1[r];
    }

    // ---- P -> LDS (C-frag -> A-frag transpose), then PV ----
#pragma unroll
    for (int r = 0; r < 4; r++) {
      int il = 4 * g16 + r;
      *(unsigned short*)(P + il * 80 + l15 * 2) = f2bf(p0[r]);
      *(unsigned short*)(P + il * 80 + 32 + l15 * 2) = f2bf(p1[r]);
    }
    short8 paf = *(const short8*)(P + l15 * 80 + g16 * 16);
#pragma unroll
    for (int nt = 0; nt < 16; nt++) {
      short8 vfr = *(const short8*)(Vw + (nt * 16 + l15) * 64 + vsel);
      zacc[nt] = MFMA16(paf, vfr, zacc[nt]);
    }

    if (more) {
      __syncthreads();
#pragma unroll
      for (int ii = 0; ii < 4; ii++) *(short8*)(Kw + kofs_w[ii]) = kreg[ii];
#pragma unroll
      for (int ii = 0; ii < 4; ii++) *(short8*)(Vw + vofs_w[ii]) = vreg[ii];
      __syncthreads();
    }
  }

  // ---- finish per-row sums (reduce partials across l15 lanes) ----
#pragma unroll
  for (int off = 1; off < 16; off <<= 1)
#pragma unroll
    for (int r = 0; r < 4; r++) ls[r] += __shfl_xor(ls[r], off);

  // ---- combine wavegroup partials ----
  __syncthreads();
  if (l15 == 0) {
#pragma unroll
    for (int r = 0; r < 4; r++) {
      int lr = 4 * g16 + r;
      mlbuf[(wv * 16 + lr) * 2] = m[r];
      mlbuf[(wv * 16 + lr) * 2 + 1] = ls[r];
    }
  }
  __syncthreads();
  const float* mlp = mlbuf + ((wv ^ 4) * 16) * 2;
  float coef[4];
#pragma unroll
  for (int r = 0; r < 4; r++) {
    int lr = 4 * g16 + r;
    float m1 = mlp[lr * 2], l1 = mlp[lr * 2 + 1];
    float M = fmaxf(m[r], m1);
    float a0 = __expf(m[r] - M), a1 = __expf(m1 - M);
    float L = a0 * ls[r] + a1 * l1;
    coef[r] = a0 / L;
  }
  if (wg == 1) {
#pragma unroll
    for (int r = 0; r < 4; r++) {
      float* zb = zbuf + (wq * 16 + 4 * g16 + r) * 256;
#pragma unroll
      for (int nt = 0; nt < 16; nt++)
        zb[nt * 16 + l15] = zacc[nt][r] * coef[r];
    }
  }
  __syncthreads();
  if (wg == 0) {
#pragma unroll
    for (int r = 0; r < 4; r++) {
      int lr = 4 * g16 + r;
      const float* zb = zbuf + (wq * 16 + lr) * 256;
      unsigned short* dst = zT + (size_t)(b * N + q0 + wq * 16 + lr) * C;
#pragma unroll
      for (int nt = 0; nt < 16; nt++)
        dst[nt * 16 + l15] = f2bf(zacc[nt][r] * coef[r] + zb[nt * 16 + l15]);
    }
  }
}

// ---------------------------------------------------------------------------
// Kernel 2.5: w4 f32 -> bf16 (one-time prep; removes per-block conversion VALU)
// ---------------------------------------------------------------------------
__global__ __launch_bounds__(256) void w4prep_kernel(
    const float* __restrict__ w4, unsigned short* __restrict__ w4b) {
  int i = (blockIdx.x * 256 + threadIdx.x) * 4;
  f32x4 v = *(const f32x4*)(w4 + i);
  short4v o;
#pragma unroll
  for (int e = 0; e < 4; e++) o[e] = (short)f2bf(v[e]);
  *(short4v*)(w4b + i) = o;
}

// ---------------------------------------------------------------------------
// Kernel 3: y = w4 @ z + b4 -> BN(eval) -> mish -> + rgb. f32 out.
// grid: (ntile=128, b=4); block 256 (4 waves; wave owns 64 cout x 32 n).
// ---------------------------------------------------------------------------
__global__ __launch_bounds__(256) void out_kernel(
    const unsigned short* __restrict__ zT, const unsigned short* __restrict__ w4b,
    const float* __restrict__ b4, const float* __restrict__ gamma,
    const float* __restrict__ beta, const float* __restrict__ rmean,
    const float* __restrict__ rvar, const float* __restrict__ rgb,
    float* __restrict__ out) {
  const int tid = threadIdx.x;
  const int b = blockIdx.y;
  const int n0 = blockIdx.x * 32;
  const int wv_ = tid >> 6, lane = tid & 63, l15 = lane & 15, g16 = lane >> 4;
  const f32x4 zero4 = {0.f, 0.f, 0.f, 0.f};

  f32x4 acc[4][2];  // [mt over cout][nt over n]
#pragma unroll
  for (int i = 0; i < 4; i++)
#pragma unroll
    for (int j = 0; j < 2; j++) acc[i][j] = zero4;

#pragma unroll
  for (int kk = 0; kk < 8; kk++) {
    short8 bfr[2];
#pragma unroll
    for (int nt = 0; nt < 2; nt++)
      bfr[nt] = *(const short8*)(zT + (size_t)(b * N + n0 + nt * 16 + l15) * C +
                                 kk * 32 + 8 * g16);
    short8 afr[4];
#pragma unroll
    for (int mt = 0; mt < 4; mt++)
      afr[mt] = *(const short8*)(w4b + (size_t)(wv_ * 64 + mt * 16 + l15) * C +
                                 kk * 32 + 8 * g16);
#pragma unroll
    for (int mt = 0; mt < 4; mt++)
#pragma unroll
      for (int nt = 0; nt < 2; nt++)
        acc[mt][nt] = MFMA16(afr[mt], bfr[nt], acc[mt][nt]);
  }

#pragma unroll
  for (int mt = 0; mt < 4; mt++)
#pragma unroll
    for (int r = 0; r < 4; r++) {
      int co = wv_ * 64 + mt * 16 + 4 * g16 + r;
      float bb = b4[co];
      float inv = gamma[co] * rsqrtf(rvar[co] + 1e-5f);
      float sh = beta[co] - rmean[co] * inv;
#pragma unroll
      for (int nt = 0; nt < 2; nt++) {
        int n = n0 + nt * 16 + l15;
        size_t idx = (size_t)(b * C + co) * N + n;
        float yv = acc[mt][nt][r] + bb;
        float tv = yv * inv + sh;
        // mish(t) = t * tanh(softplus(t)) = t * (u^2-1)/(u^2+1), u = 1+e^t
        float s = __expf(fminf(tv, 40.f));
        float u = 1.f + s;
        float u2 = u * u;
        float mish = tv * ((u2 - 1.f) / (u2 + 1.f));
        out[idx] = rgb[idx] + mish;
      }
    }
}

// ---------------------------------------------------------------------------
extern "C" void kernel_launch(void* const* d_in, const int* in_sizes, int n_in,
                              void* d_out, int out_size, void* d_ws,
                              size_t ws_size, hipStream_t stream) {
  const float* rgb = (const float*)d_in[0];
  const float* ir = (const float*)d_in[1];
  const float* wq = (const float*)d_in[2];
  const float* bq = (const float*)d_in[3];
  const float* wk = (const float*)d_in[4];
  const float* bk = (const float*)d_in[5];
  const float* wvv = (const float*)d_in[6];
  const float* bvv = (const float*)d_in[7];
  const float* w4 = (const float*)d_in[8];
  const float* b4 = (const float*)d_in[9];
  const float* gamma = (const float*)d_in[10];
  const float* beta = (const float*)d_in[11];
  const float* rmean = (const float*)d_in[12];
  const float* rvar = (const float*)d_in[13];

  unsigned short* qT = (unsigned short*)d_ws;          // [B][N][C] bf16
  unsigned short* kT = qT + (size_t)B * N * C;         // [B][N][C] bf16
  unsigned short* vN = kT + (size_t)B * N * C;         // [B][C][N] bf16
  unsigned short* zT = vN + (size_t)B * N * C;         // [B][N][C] bf16
  unsigned short* w4b = zT + (size_t)B * N * C;        // [C][C] bf16

  w4prep_kernel<<<64, 256, 0, stream>>>(w4, w4b);
  qkv_kernel<<<dim3(16, 16, 3), 256, 0, stream>>>(rgb, ir, wq, bq, wk, bk, wvv,
                                                  bvv, qT, kT, vN);
  attn_kernel<<<dim3(64, 4), 512, 0, stream>>>(qT, kT, vN, zT);
  out_kernel<<<dim3(128, 4), 256, 0, stream>>>(zT, w4b, b4, gamma, beta, rmean,
                                               rvar, rgb, (float*)d_out);
}

// Round 3
// 293.083 us; speedup vs baseline: 1.4640x; 1.0856x over previous
//
#include <hip/hip_runtime.h>
#include <stdint.h>
#include <stddef.h>

typedef short short8 __attribute__((ext_vector_type(8)));
typedef short short4v __attribute__((ext_vector_type(4)));
typedef float f32x4 __attribute__((ext_vector_type(4)));
typedef float f32x16 __attribute__((ext_vector_type(16)));
typedef unsigned int u32x4 __attribute__((ext_vector_type(4)));

#define MFMA16(a, b, c) __builtin_amdgcn_mfma_f32_16x16x32_bf16(a, b, c, 0, 0, 0)
#define MFMA32(a, b, c) __builtin_amdgcn_mfma_f32_32x32x16_bf16(a, b, c, 0, 0, 0)
#define P32SWAP(a, b) asm("v_permlane32_swap_b32 %0, %1" : "+v"(a), "+v"(b))

static constexpr int B = 4, C = 256, CG = 64, N = 4096;

__device__ __forceinline__ unsigned short f2bf(float f) {
  unsigned int u = __builtin_bit_cast(unsigned int, f);
  u += 0x7FFFu + ((u >> 16) & 1u);
  return (unsigned short)(u >> 16);
}

__device__ __forceinline__ void async16(const void* g, void* l) {
  __builtin_amdgcn_global_load_lds(
      (const __attribute__((address_space(1))) unsigned int*)g,
      (__attribute__((address_space(3))) unsigned int*)l, 16, 0, 0);
}

// ---------------------------------------------------------------------------
// Kernel 1: grouped 1x1 convs -> qT [b][n][c] (scaled by c^-0.5), kT [b][n][c],
// v [b][c][n], all bf16 (stored as u16). grid (16,16,3), block 256.
// ---------------------------------------------------------------------------
__global__ __launch_bounds__(256) void qkv_kernel(
    const float* __restrict__ rgb, const float* __restrict__ ir,
    const float* __restrict__ wq, const float* __restrict__ bq,
    const float* __restrict__ wk, const float* __restrict__ bk,
    const float* __restrict__ wvv, const float* __restrict__ bvv,
    unsigned short* __restrict__ qT, unsigned short* __restrict__ kT,
    unsigned short* __restrict__ vN) {
  __shared__ unsigned char xTs[256 * 144];
  __shared__ unsigned char wls[64 * 144];

  const int tid = threadIdx.x;
  const int which = blockIdx.z;
  const int bg = blockIdx.y;
  const int b = bg >> 2, g = bg & 3;
  const int n0 = blockIdx.x * 256;

  const float* x = (which == 0) ? rgb : ir;
  const float* w = (which == 0) ? wq : (which == 1 ? wk : wvv);
  const float* bias = (which == 0) ? bq : (which == 1 ? bk : bvv);

  {
    const int p = tid & 31;
    const int jseg = (tid >> 5) * 32;
    const float* r0 = x + ((size_t)(b * C + g * CG + 2 * p) * N + n0 + jseg);
    const float* r1 = r0 + N;
#pragma unroll
    for (int ii = 0; ii < 8; ii++) {
      f32x4 a = *(const f32x4*)(r0 + 4 * ii);
      f32x4 c2 = *(const f32x4*)(r1 + 4 * ii);
#pragma unroll
      for (int e = 0; e < 4; e++) {
        unsigned int pk =
            (unsigned int)f2bf(a[e]) | ((unsigned int)f2bf(c2[e]) << 16);
        *(unsigned int*)(xTs + (size_t)(jseg + 4 * ii + e) * 144 + 4 * p) = pk;
      }
    }
  }
  {
    const int o = tid >> 2;
    const int cs = (tid & 3) * 16;
    const float* wr = w + (size_t)g * CG * CG + (size_t)o * CG + cs;
#pragma unroll
    for (int i = 0; i < 8; i++) {
      unsigned int pk = (unsigned int)f2bf(wr[2 * i]) |
                        ((unsigned int)f2bf(wr[2 * i + 1]) << 16);
      *(unsigned int*)(wls + (size_t)o * 144 + (cs + 2 * i) * 2) = pk;
    }
  }
  __syncthreads();

  const int wv_ = tid >> 6, lane = tid & 63, l15 = lane & 15, g16 = lane >> 4;
  const f32x4 zero4 = {0.f, 0.f, 0.f, 0.f};
  f32x4 acc[4][4];
#pragma unroll
  for (int i = 0; i < 4; i++)
#pragma unroll
    for (int j = 0; j < 4; j++) acc[i][j] = zero4;

  if (which < 2) {
#pragma unroll
    for (int kk = 0; kk < 2; kk++) {
      short8 af[4], bfr[4];
#pragma unroll
      for (int mt = 0; mt < 4; mt++)
        af[mt] = *(const short8*)(xTs +
                                  (size_t)(wv_ * 64 + mt * 16 + l15) * 144 +
                                  (kk * 32 + 8 * g16) * 2);
#pragma unroll
      for (int nt = 0; nt < 4; nt++)
        bfr[nt] = *(const short8*)(wls + (size_t)(nt * 16 + l15) * 144 +
                                   (kk * 32 + 8 * g16) * 2);
#pragma unroll
      for (int mt = 0; mt < 4; mt++)
#pragma unroll
        for (int nt = 0; nt < 4; nt++)
          acc[mt][nt] = MFMA16(af[mt], bfr[nt], acc[mt][nt]);
    }
    unsigned short* out = (which == 0) ? qT : kT;
    const float qs = (which == 0) ? 0.0625f : 1.0f;
#pragma unroll
    for (int mt = 0; mt < 4; mt++)
#pragma unroll
      for (int nt = 0; nt < 4; nt++)
#pragma unroll
        for (int r = 0; r < 4; r++) {
          int nl = wv_ * 64 + mt * 16 + 4 * g16 + r;
          int co = nt * 16 + l15;
          float val = (acc[mt][nt][r] + bias[g * CG + co]) * qs;
          out[(size_t)(b * N + n0 + nl) * C + g * CG + co] = f2bf(val);
        }
  } else {
#pragma unroll
    for (int kk = 0; kk < 2; kk++) {
      short8 af[4], bfr[4];
#pragma unroll
      for (int mt = 0; mt < 4; mt++)
        af[mt] = *(const short8*)(wls + (size_t)(mt * 16 + l15) * 144 +
                                  (kk * 32 + 8 * g16) * 2);
#pragma unroll
      for (int nt = 0; nt < 4; nt++)
        bfr[nt] = *(const short8*)(xTs +
                                   (size_t)(wv_ * 64 + nt * 16 + l15) * 144 +
                                   (kk * 32 + 8 * g16) * 2);
#pragma unroll
      for (int mt = 0; mt < 4; mt++)
#pragma unroll
        for (int nt = 0; nt < 4; nt++)
          acc[mt][nt] = MFMA16(af[mt], bfr[nt], acc[mt][nt]);
    }
#pragma unroll
    for (int mt = 0; mt < 4; mt++)
#pragma unroll
      for (int nt = 0; nt < 4; nt++)
#pragma unroll
        for (int r = 0; r < 4; r++) {
          int co = mt * 16 + 4 * g16 + r;
          int nl = wv_ * 64 + nt * 16 + l15;
          float val = acc[mt][nt][r] + bias[g * CG + co];
          vN[(size_t)(b * C + g * CG + co) * N + n0 + nl] = f2bf(val);
        }
  }
}

// ---------------------------------------------------------------------------
// Kernel 2: flash attention, 32x32 swapped-operand structure.
// grid 256 (1 block/CU), block 512 = 8 waves = 4 kv-quarters x 2 q-subtiles.
// Each wave: 32 q-rows x 1024 keys (32 steps of 32 keys). q_w=32.
// S^T = mfma32(K, Q); softmax in-register; P->B-frag via permlane32_swap;
// z^T = mfma32(V^T, P^T). K/V staged via global_load_lds with pre-swizzled
// source (rule #21); 4-way split-K combine through LDS.
// ---------------------------------------------------------------------------
__global__ __launch_bounds__(512, 2) void attn_kernel(
    const unsigned short* __restrict__ qT, const unsigned short* __restrict__ kT,
    const unsigned short* __restrict__ vN, unsigned short* __restrict__ zT) {
  // [0,131072): 4 x (K tile 16KB + V tile 16KB)
  // epilogue overlay: zbufA f32[64][258] @0, zbufB @66048, mlbuf @132096
  __shared__ __align__(16) unsigned char smem[134144];

  const int tid = threadIdx.x;
  const int pid = blockIdx.x;                 // XCD-chunked swizzle (bijective, 256%8==0)
  const int lg = (pid & 7) * 32 + (pid >> 3);
  const int b = lg >> 6;
  const int q0 = (lg & 63) * 64;
  const int wv = tid >> 6, lane = tid & 63;
  const int l31 = lane & 31, h = lane >> 5;
  const int qsub = wv & 1, kvq = wv >> 1;

  unsigned char* Kw = smem + kvq * 32768;
  unsigned char* Vw = Kw + 16384;
  float* zbufA = (float*)smem;
  float* zbufB = (float*)(smem + 66048);
  float* mlb = (float*)(smem + 132096);

  // ---- Q fragments: B-layout [k=c][n=q], n=l31, k=8h+{0..7} per 16-c window
  short8 qf[16];
  {
    const unsigned short* qrow =
        qT + (size_t)(b * N + q0 + qsub * 32 + l31) * C + 8 * h;
#pragma unroll
    for (int kk = 0; kk < 16; kk++) qf[kk] = *(const short8*)(qrow + 16 * kk);
  }

  f32x16 zacc[8];
#pragma unroll
  for (int cs = 0; cs < 8; cs++)
#pragma unroll
    for (int e = 0; e < 16; e++) zacc[cs][e] = 0.f;

  float mr = 4.0f, lsum = 0.f;

  // ---- staging bases (this wave stages half of its wg's K and V tiles) ----
  const unsigned short* kq = kT + ((size_t)b * N + kvq * 1024) * C;
  const unsigned short* vq = vN + (size_t)(b * C) * N + kvq * 1024;

  auto stage = [&](int jt) {
#pragma unroll
    for (int i = 0; i < 8; i++) {
      int p = (qsub * 8 + i) * 64 + lane;     // K chunk id 0..1023
      int r = p >> 5, cc = p & 31;
      int sc = (cc & 24) | ((cc & 7) ^ (r & 7));  // inverse-swizzled source
      async16(kq + (size_t)(jt * 32 + r) * C + sc * 8,
              Kw + (qsub * 8 + i) * 1024);
    }
#pragma unroll
    for (int i = 0; i < 8; i++) {
      int p = (qsub * 8 + i) * 64 + lane;     // V chunk id 0..1023
      int c = p >> 2, ch = p & 3;
      int sch = ch ^ ((c >> 1) & 3);
      async16(vq + (size_t)c * N + jt * 32 + sch * 8,
              Vw + (qsub * 8 + i) * 1024);
    }
  };

  // ---- read geometry ----
  unsigned char* krow = Kw + l31 * 512;       // K row j = l31
  const int kx = (l31 & 7) << 4;
  const int vx = ((l31 >> 1) & 3) << 4;

  stage(0);
  __syncthreads();

  for (int jt = 0; jt < 32; jt++) {
    // ---- S^T[j][q] = K . Q^T over c=256 ----
    f32x16 s;
#pragma unroll
    for (int e = 0; e < 16; e++) s[e] = 0.f;
#pragma unroll
    for (int kk = 0; kk < 16; kk++) {
      short8 kf = *(const short8*)(krow + ((32 * kk + 16 * h) ^ kx));
      s = MFMA32(kf, qf[kk], s);
    }

    // ---- in-register online softmax (lane owns q=l31, 16 j's per half) ----
    float rmx = s[0];
#pragma unroll
    for (int r = 1; r < 16; r++) rmx = fmaxf(rmx, s[r]);
    rmx = fmaxf(rmx, __shfl_xor(rmx, 32));
    if (__any(rmx > mr + 8.f)) {              // defer-max (rare path)
      float mn = fmaxf(mr, rmx);
      float al = __expf(mr - mn);
      mr = mn;
      lsum *= al;
#pragma unroll
      for (int cs = 0; cs < 8; cs++) zacc[cs] *= al;
    }
    float p[16];
    float psum = 0.f;
#pragma unroll
    for (int r = 0; r < 16; r++) {
      p[r] = __expf(s[r] - mr);
      psum += p[r];
    }
    lsum += psum;

    // ---- P^T -> B-fragments via permlane32_swap (no LDS) ----
    unsigned int w[8];
#pragma unroll
    for (int e = 0; e < 8; e++)
      w[e] = (unsigned int)f2bf(p[2 * e]) |
             ((unsigned int)f2bf(p[2 * e + 1]) << 16);
    P32SWAP(w[0], w[2]);
    P32SWAP(w[1], w[3]);
    P32SWAP(w[4], w[6]);
    P32SWAP(w[5], w[7]);
    u32x4 t0 = {w[0], w[1], w[2], w[3]};
    u32x4 t1 = {w[4], w[5], w[6], w[7]};
    short8 pf0 = __builtin_bit_cast(short8, t0);
    short8 pf1 = __builtin_bit_cast(short8, t1);

    // ---- z^T += V^T . P^T ----
#pragma unroll
    for (int cs = 0; cs < 8; cs++) {
      unsigned char* vr = Vw + (cs * 32 + l31) * 64;
      short8 v0 = *(const short8*)(vr + ((16 * h) ^ vx));
      zacc[cs] = MFMA32(v0, pf0, zacc[cs]);
      short8 v1 = *(const short8*)(vr + ((32 + 16 * h) ^ vx));
      zacc[cs] = MFMA32(v1, pf1, zacc[cs]);
    }

    __syncthreads();                           // all waves done reading tile jt
    if (jt + 1 < 32) stage(jt + 1);            // async DMA into same buffers
    __syncthreads();                           // barrier drains vmcnt(0)
  }

  // ---- split-K-4 combine ----
  float ls_tot = lsum + __shfl_xor(lsum, 32);
  if (h == 0) {
    mlb[(wv * 32 + l31) * 2] = mr;
    mlb[(wv * 32 + l31) * 2 + 1] = ls_tot;
  }
  __syncthreads();
  float mj[4], lj[4];
#pragma unroll
  for (int j = 0; j < 4; j++) {
    int widx = j * 2 + qsub;
    mj[j] = mlb[(widx * 32 + l31) * 2];
    lj[j] = mlb[(widx * 32 + l31) * 2 + 1];
  }
  float M = fmaxf(fmaxf(mj[0], mj[1]), fmaxf(mj[2], mj[3]));
  float L = 0.f;
#pragma unroll
  for (int j = 0; j < 4; j++) L += __expf(mj[j] - M) * lj[j];
  float coef = __expf(mr - M) / L;

  float* buf = (kvq >> 1) ? zbufB : zbufA;
  const int qloc = qsub * 32 + l31;
  if (kvq & 1) {                               // quarters 1,3 scatter
#pragma unroll
    for (int cs = 0; cs < 8; cs++)
#pragma unroll
      for (int r = 0; r < 16; r++) {
        int c = cs * 32 + (r & 3) + 8 * (r >> 2) + 4 * h;
        buf[qloc * 258 + c] = coef * zacc[cs][r];
      }
  }
  __syncthreads();
  if (!(kvq & 1)) {                            // quarters 0,2 add
#pragma unroll
    for (int cs = 0; cs < 8; cs++)
#pragma unroll
      for (int r = 0; r < 16; r++) {
        int c = cs * 32 + (r & 3) + 8 * (r >> 2) + 4 * h;
        float* a = &buf[qloc * 258 + c];
        *a = *a + coef * zacc[cs][r];
      }
  }
  __syncthreads();
  // ---- final: zT[q][c] = A + B, bf16, coalesced ----
  {
    int q = tid >> 3, cseg = (tid & 7) * 32;
    const float* A = zbufA + q * 258 + cseg;
    const float* Bq = zbufB + q * 258 + cseg;
    unsigned short* dst = zT + (size_t)(b * N + q0 + q) * C + cseg;
#pragma unroll
    for (int g = 0; g < 4; g++) {
      unsigned int wo[4];
#pragma unroll
      for (int e = 0; e < 4; e++) {
        float lo = A[g * 8 + 2 * e] + Bq[g * 8 + 2 * e];
        float hi = A[g * 8 + 2 * e + 1] + Bq[g * 8 + 2 * e + 1];
        wo[e] = (unsigned int)f2bf(lo) | ((unsigned int)f2bf(hi) << 16);
      }
      u32x4 tw = {wo[0], wo[1], wo[2], wo[3]};
      *(short8*)(dst + g * 8) = __builtin_bit_cast(short8, tw);
    }
  }
}

// ---------------------------------------------------------------------------
// Kernel 2.5: w4 f32 -> bf16
// ---------------------------------------------------------------------------
__global__ __launch_bounds__(256) void w4prep_kernel(
    const float* __restrict__ w4, unsigned short* __restrict__ w4b) {
  int i = (blockIdx.x * 256 + threadIdx.x) * 4;
  f32x4 v = *(const f32x4*)(w4 + i);
  short4v o;
#pragma unroll
  for (int e = 0; e < 4; e++) o[e] = (short)f2bf(v[e]);
  *(short4v*)(w4b + i) = o;
}

// ---------------------------------------------------------------------------
// Kernel 3: y = w4 @ z + b4 -> BN(eval) -> mish -> + rgb. f32 out.
// grid (128,4), block 256.
// ---------------------------------------------------------------------------
__global__ __launch_bounds__(256) void out_kernel(
    const unsigned short* __restrict__ zT, const unsigned short* __restrict__ w4b,
    const float* __restrict__ b4, const float* __restrict__ gamma,
    const float* __restrict__ beta, const float* __restrict__ rmean,
    const float* __restrict__ rvar, const float* __restrict__ rgb,
    float* __restrict__ out) {
  const int tid = threadIdx.x;
  const int b = blockIdx.y;
  const int n0 = blockIdx.x * 32;
  const int wv_ = tid >> 6, lane = tid & 63, l15 = lane & 15, g16 = lane >> 4;
  const f32x4 zero4 = {0.f, 0.f, 0.f, 0.f};

  f32x4 acc[4][2];
#pragma unroll
  for (int i = 0; i < 4; i++)
#pragma unroll
    for (int j = 0; j < 2; j++) acc[i][j] = zero4;

#pragma unroll
  for (int kk = 0; kk < 8; kk++) {
    short8 bfr[2];
#pragma unroll
    for (int nt = 0; nt < 2; nt++)
      bfr[nt] = *(const short8*)(zT + (size_t)(b * N + n0 + nt * 16 + l15) * C +
                                 kk * 32 + 8 * g16);
    short8 afr[4];
#pragma unroll
    for (int mt = 0; mt < 4; mt++)
      afr[mt] = *(const short8*)(w4b + (size_t)(wv_ * 64 + mt * 16 + l15) * C +
                                 kk * 32 + 8 * g16);
#pragma unroll
    for (int mt = 0; mt < 4; mt++)
#pragma unroll
      for (int nt = 0; nt < 2; nt++)
        acc[mt][nt] = MFMA16(afr[mt], bfr[nt], acc[mt][nt]);
  }

#pragma unroll
  for (int mt = 0; mt < 4; mt++)
#pragma unroll
    for (int r = 0; r < 4; r++) {
      int co = wv_ * 64 + mt * 16 + 4 * g16 + r;
      float bb = b4[co];
      float inv = gamma[co] * rsqrtf(rvar[co] + 1e-5f);
      float sh = beta[co] - rmean[co] * inv;
#pragma unroll
      for (int nt = 0; nt < 2; nt++) {
        int n = n0 + nt * 16 + l15;
        size_t idx = (size_t)(b * C + co) * N + n;
        float yv = acc[mt][nt][r] + bb;
        float tv = yv * inv + sh;
        float s = __expf(fminf(tv, 40.f));
        float u = 1.f + s;
        float u2 = u * u;
        float mish = tv * ((u2 - 1.f) / (u2 + 1.f));
        out[idx] = rgb[idx] + mish;
      }
    }
}

// ---------------------------------------------------------------------------
extern "C" void kernel_launch(void* const* d_in, const int* in_sizes, int n_in,
                              void* d_out, int out_size, void* d_ws,
                              size_t ws_size, hipStream_t stream) {
  const float* rgb = (const float*)d_in[0];
  const float* ir = (const float*)d_in[1];
  const float* wq = (const float*)d_in[2];
  const float* bq = (const float*)d_in[3];
  const float* wk = (const float*)d_in[4];
  const float* bk = (const float*)d_in[5];
  const float* wvv = (const float*)d_in[6];
  const float* bvv = (const float*)d_in[7];
  const float* w4 = (const float*)d_in[8];
  const float* b4 = (const float*)d_in[9];
  const float* gamma = (const float*)d_in[10];
  const float* beta = (const float*)d_in[11];
  const float* rmean = (const float*)d_in[12];
  const float* rvar = (const float*)d_in[13];

  unsigned short* qT = (unsigned short*)d_ws;          // [B][N][C] bf16
  unsigned short* kT = qT + (size_t)B * N * C;         // [B][N][C] bf16
  unsigned short* vN = kT + (size_t)B * N * C;         // [B][C][N] bf16
  unsigned short* zT = vN + (size_t)B * N * C;         // [B][N][C] bf16
  unsigned short* w4b = zT + (size_t)B * N * C;        // [C][C] bf16

  w4prep_kernel<<<64, 256, 0, stream>>>(w4, w4b);
  qkv_kernel<<<dim3(16, 16, 3), 256, 0, stream>>>(rgb, ir, wq, bq, wk, bk, wvv,
                                                  bvv, qT, kT, vN);
  attn_kernel<<<256, 512, 0, stream>>>(qT, kT, vN, zT);
  out_kernel<<<dim3(128, 4), 256, 0, stream>>>(zT, w4b, b4, gamma, beta, rmean,
                                               rvar, rgb, (float*)d_out);
}

// Round 4
// 220.079 us; speedup vs baseline: 1.9496x; 1.3317x over previous
//
#include <hip/hip_runtime.h>
#include <stdint.h>
#include <stddef.h>

typedef short short8 __attribute__((ext_vector_type(8)));
typedef short short4v __attribute__((ext_vector_type(4)));
typedef float f32x4 __attribute__((ext_vector_type(4)));
typedef float f32x16 __attribute__((ext_vector_type(16)));
typedef unsigned int u32x4 __attribute__((ext_vector_type(4)));

#define MFMA16(a, b, c) __builtin_amdgcn_mfma_f32_16x16x32_bf16(a, b, c, 0, 0, 0)
#define MFMA32(a, b, c) __builtin_amdgcn_mfma_f32_32x32x16_bf16(a, b, c, 0, 0, 0)
#define P32SWAP(a, b) asm("v_permlane32_swap_b32 %0, %1" : "+v"(a), "+v"(b))

static constexpr int B = 4, C = 256, CG = 64, N = 4096;

__device__ __forceinline__ unsigned short f2bf(float f) {
  unsigned int u = __builtin_bit_cast(unsigned int, f);
  u += 0x7FFFu + ((u >> 16) & 1u);
  return (unsigned short)(u >> 16);
}

__device__ __forceinline__ void async16(const void* g, void* l) {
  __builtin_amdgcn_global_load_lds(
      (const __attribute__((address_space(1))) unsigned int*)g,
      (__attribute__((address_space(3))) unsigned int*)l, 16, 0, 0);
}

// ---------------------------------------------------------------------------
// Kernel 1: grouped 1x1 convs -> qT [b][n][c] (scaled by c^-0.5), kT [b][n][c],
// v [b][c][n], all bf16 (stored as u16). grid (16,16,3), block 256.
// ---------------------------------------------------------------------------
__global__ __launch_bounds__(256) void qkv_kernel(
    const float* __restrict__ rgb, const float* __restrict__ ir,
    const float* __restrict__ wq, const float* __restrict__ bq,
    const float* __restrict__ wk, const float* __restrict__ bk,
    const float* __restrict__ wvv, const float* __restrict__ bvv,
    unsigned short* __restrict__ qT, unsigned short* __restrict__ kT,
    unsigned short* __restrict__ vN) {
  __shared__ unsigned char xTs[256 * 144];
  __shared__ unsigned char wls[64 * 144];

  const int tid = threadIdx.x;
  const int which = blockIdx.z;
  const int bg = blockIdx.y;
  const int b = bg >> 2, g = bg & 3;
  const int n0 = blockIdx.x * 256;

  const float* x = (which == 0) ? rgb : ir;
  const float* w = (which == 0) ? wq : (which == 1 ? wk : wvv);
  const float* bias = (which == 0) ? bq : (which == 1 ? bk : bvv);

  // stage xT: coalesced reads (8 consecutive lanes = 128B contiguous)
  {
    const int p = tid >> 3;           // row-pair 0..31 (cin = 2p, 2p+1)
    const int nlo = (tid & 7) * 4;    // 16B column within 128B segment
    const float* r0 = x + ((size_t)(b * C + g * CG + 2 * p) * N + n0 + nlo);
    const float* r1 = r0 + N;
#pragma unroll
    for (int seg = 0; seg < 8; seg++) {
      f32x4 a = *(const f32x4*)(r0 + seg * 32);
      f32x4 c2 = *(const f32x4*)(r1 + seg * 32);
#pragma unroll
      for (int e = 0; e < 4; e++) {
        unsigned int pk =
            (unsigned int)f2bf(a[e]) | ((unsigned int)f2bf(c2[e]) << 16);
        *(unsigned int*)(xTs + (size_t)(seg * 32 + nlo + e) * 144 + 4 * p) = pk;
      }
    }
  }
  {
    const int o = tid >> 2;
    const int cs = (tid & 3) * 16;
    const float* wr = w + (size_t)g * CG * CG + (size_t)o * CG + cs;
#pragma unroll
    for (int i = 0; i < 8; i++) {
      unsigned int pk = (unsigned int)f2bf(wr[2 * i]) |
                        ((unsigned int)f2bf(wr[2 * i + 1]) << 16);
      *(unsigned int*)(wls + (size_t)o * 144 + (cs + 2 * i) * 2) = pk;
    }
  }
  __syncthreads();

  const int wv_ = tid >> 6, lane = tid & 63, l15 = lane & 15, g16 = lane >> 4;
  const f32x4 zero4 = {0.f, 0.f, 0.f, 0.f};
  f32x4 acc[4][4];
#pragma unroll
  for (int i = 0; i < 4; i++)
#pragma unroll
    for (int j = 0; j < 4; j++) acc[i][j] = zero4;

  if (which < 2) {
#pragma unroll
    for (int kk = 0; kk < 2; kk++) {
      short8 af[4], bfr[4];
#pragma unroll
      for (int mt = 0; mt < 4; mt++)
        af[mt] = *(const short8*)(xTs +
                                  (size_t)(wv_ * 64 + mt * 16 + l15) * 144 +
                                  (kk * 32 + 8 * g16) * 2);
#pragma unroll
      for (int nt = 0; nt < 4; nt++)
        bfr[nt] = *(const short8*)(wls + (size_t)(nt * 16 + l15) * 144 +
                                   (kk * 32 + 8 * g16) * 2);
#pragma unroll
      for (int mt = 0; mt < 4; mt++)
#pragma unroll
        for (int nt = 0; nt < 4; nt++)
          acc[mt][nt] = MFMA16(af[mt], bfr[nt], acc[mt][nt]);
    }
    unsigned short* out = (which == 0) ? qT : kT;
    const float qs = (which == 0) ? 0.0625f : 1.0f;
#pragma unroll
    for (int mt = 0; mt < 4; mt++)
#pragma unroll
      for (int nt = 0; nt < 4; nt++)
#pragma unroll
        for (int r = 0; r < 4; r++) {
          int nl = wv_ * 64 + mt * 16 + 4 * g16 + r;
          int co = nt * 16 + l15;
          float val = (acc[mt][nt][r] + bias[g * CG + co]) * qs;
          out[(size_t)(b * N + n0 + nl) * C + g * CG + co] = f2bf(val);
        }
  } else {
#pragma unroll
    for (int kk = 0; kk < 2; kk++) {
      short8 af[4], bfr[4];
#pragma unroll
      for (int mt = 0; mt < 4; mt++)
        af[mt] = *(const short8*)(wls + (size_t)(mt * 16 + l15) * 144 +
                                  (kk * 32 + 8 * g16) * 2);
#pragma unroll
      for (int nt = 0; nt < 4; nt++)
        bfr[nt] = *(const short8*)(xTs +
                                   (size_t)(wv_ * 64 + nt * 16 + l15) * 144 +
                                   (kk * 32 + 8 * g16) * 2);
#pragma unroll
      for (int mt = 0; mt < 4; mt++)
#pragma unroll
        for (int nt = 0; nt < 4; nt++)
          acc[mt][nt] = MFMA16(af[mt], bfr[nt], acc[mt][nt]);
    }
#pragma unroll
    for (int mt = 0; mt < 4; mt++)
#pragma unroll
      for (int nt = 0; nt < 4; nt++)
#pragma unroll
        for (int r = 0; r < 4; r++) {
          int co = mt * 16 + 4 * g16 + r;
          int nl = wv_ * 64 + nt * 16 + l15;
          float val = acc[mt][nt][r] + bias[g * CG + co];
          vN[(size_t)(b * C + g * CG + co) * N + n0 + nl] = f2bf(val);
        }
  }
}

// ---------------------------------------------------------------------------
// Kernel 2: flash attention, 32x32 swapped-operand, 4-phase counted-vmcnt
// pipeline. grid 256 (1 block/CU), block 512 = 4 kv-quarters x 2 q-subtiles.
// Per step (32 keys): P0 QK(c0..127) | P1 QK(c128..255) | P2 sm+PV(c0..127)
// | P3 PV(c128..255). Each phase: vmcnt(8); s_barrier; issue 4 DMA loads for
// the region consumed 3 phases later. Never drains vmcnt in the loop.
// ---------------------------------------------------------------------------
__global__ __launch_bounds__(512, 2) void attn_kernel(
    const unsigned short* __restrict__ qT, const unsigned short* __restrict__ kT,
    const unsigned short* __restrict__ vN, unsigned short* __restrict__ zT) {
  // [0,131072): 4 x (K tile 16KB [half][j32][256B] + V tile 16KB [half][c128][64B])
  // epilogue overlay: zbufA f32[64][258] @0, zbufB @66048, mlbuf @132096
  __shared__ __align__(16) unsigned char smem[134144];

  const int tid = threadIdx.x;
  const int pid = blockIdx.x;  // XCD-chunked swizzle (bijective, 256%8==0)
  const int lg = (pid & 7) * 32 + (pid >> 3);
  const int b = lg >> 6;
  const int q0 = (lg & 63) * 64;
  const int wv = tid >> 6, lane = tid & 63;
  const int l31 = lane & 31, hj = lane >> 5;
  const int qsub = wv & 1, kvq = wv >> 1;

  unsigned char* Kw = smem + kvq * 32768;
  unsigned char* Vw = Kw + 16384;
  float* zbufA = (float*)smem;
  float* zbufB = (float*)(smem + 66048);
  float* mlb = (float*)(smem + 132096);

  // ---- Q fragments (registers, whole kernel) ----
  short8 qf[16];
  {
    const unsigned short* qrow =
        qT + (size_t)(b * N + q0 + qsub * 32 + l31) * C + 8 * hj;
#pragma unroll
    for (int kk = 0; kk < 16; kk++) qf[kk] = *(const short8*)(qrow + 16 * kk);
  }

  f32x16 zacc[8];
#pragma unroll
  for (int cs = 0; cs < 8; cs++)
#pragma unroll
    for (int e = 0; e < 16; e++) zacc[cs][e] = 0.f;
  float mr = 4.0f, lsum = 0.f;

  // ---- staging per-lane geometry ----
  const unsigned short* kq = kT + ((size_t)b * N + kvq * 1024) * C;
  const unsigned short* vq = vN + (size_t)(b * C) * N + kvq * 1024;
  const int t128 = qsub * 64 + lane;  // 0..127 within quarter
  const int r0 = t128 >> 4;           // K row base 0..7
  const int ccp = t128 & 15;          // K physical 16B-chunk in row
  const int cl0 = t128 >> 2;          // V row base 0..31
  const int chl = (t128 & 3) ^ ((cl0 >> 1) & 3);  // V logical chunk (pre-inv-swz)

  // K: LDS byte = h*8192 + r*256 + ccp*16 ; src cc_logical = ccp ^ (r&15)
  auto stK = [&](int jt, int h) {
#pragma unroll
    for (int i = 0; i < 4; i++) {
      const unsigned short* src = kq + (size_t)(jt * 32 + i * 8 + r0) * C +
                                  h * 128 + ((ccp ^ r0 ^ ((i & 1) << 3)) << 3);
      async16(src, Kw + h * 8192 + (i * 128 + qsub * 64) * 16);
    }
  };
  // V: LDS byte = h*8192 + c_local*64 + chp*16 ; src chunk = chp ^ ((c>>1)&3)
  auto stV = [&](int jt, int h) {
#pragma unroll
    for (int i = 0; i < 4; i++) {
      const unsigned short* src =
          vq + (size_t)(h * 128 + i * 32 + cl0) * N + jt * 32 + chl * 8;
      async16(src, Vw + h * 8192 + (i * 128 + qsub * 64) * 16);
    }
  };

  // ---- read geometry ----
  const int kxm = l31 & 15;           // K read swizzle mask
  const int vxm = (l31 >> 1) & 3;     // V read swizzle mask
  unsigned char* krow = Kw + l31 * 256;

  // ---- prologue: stage full tile 0, drain once ----
  stK(0, 0);
  stK(0, 1);
  stV(0, 0);
  stV(0, 1);
  asm volatile("s_waitcnt vmcnt(0)" ::: "memory");
  __builtin_amdgcn_s_barrier();

  short8 pf0, pf1;
  for (int jt = 0; jt < 32; jt++) {
    // ---- P0: QK c-half 0; issue V1[jt] region loads (consumed P3) ----
    asm volatile("s_waitcnt vmcnt(8)" ::: "memory");
    __builtin_amdgcn_s_barrier();
    stV(jt, 1);
    f32x16 s;
#pragma unroll
    for (int e = 0; e < 16; e++) s[e] = 0.f;
#pragma unroll
    for (int kk = 0; kk < 8; kk++) {
      short8 kf =
          *(const short8*)(krow + (((kk * 2 + hj) ^ kxm) << 4));
      s = MFMA32(kf, qf[kk], s);
    }
    // ---- P1: QK c-half 1; issue K0[jt+1] ----
    asm volatile("s_waitcnt vmcnt(8)" ::: "memory");
    __builtin_amdgcn_s_barrier();
    stK(jt + 1, 0);
#pragma unroll
    for (int kk = 8; kk < 16; kk++) {
      short8 kf = *(const short8*)(krow + 8192 +
                                   ((((kk & 7) * 2 + hj) ^ kxm) << 4));
      s = MFMA32(kf, qf[kk], s);
    }
    // ---- P2: softmax + PV c-half 0; issue K1[jt+1] ----
    asm volatile("s_waitcnt vmcnt(8)" ::: "memory");
    __builtin_amdgcn_s_barrier();
    stK(jt + 1, 1);
    {
      float rmx = s[0];
#pragma unroll
      for (int r = 1; r < 16; r++) rmx = fmaxf(rmx, s[r]);
      rmx = fmaxf(rmx, __shfl_xor(rmx, 32));
      if (__any(rmx > mr + 8.f)) {  // defer-max (rare path)
        float mn = fmaxf(mr, rmx);
        float al = __expf(mr - mn);
        mr = mn;
        lsum *= al;
#pragma unroll
        for (int cs = 0; cs < 8; cs++) zacc[cs] *= al;
      }
      float psum = 0.f;
#pragma unroll
      for (int r = 0; r < 16; r++) {
        s[r] = __expf(s[r] - mr);
        psum += s[r];
      }
      lsum += psum;
      unsigned int w[8];
#pragma unroll
      for (int e = 0; e < 8; e++)
        w[e] = (unsigned int)f2bf(s[2 * e]) |
               ((unsigned int)f2bf(s[2 * e + 1]) << 16);
      P32SWAP(w[0], w[2]);
      P32SWAP(w[1], w[3]);
      P32SWAP(w[4], w[6]);
      P32SWAP(w[5], w[7]);
      u32x4 t0 = {w[0], w[1], w[2], w[3]};
      u32x4 t1 = {w[4], w[5], w[6], w[7]};
      pf0 = __builtin_bit_cast(short8, t0);
      pf1 = __builtin_bit_cast(short8, t1);
    }
#pragma unroll
    for (int cs = 0; cs < 4; cs++) {
      unsigned char* vr = Vw + (cs * 32 + l31) * 64;
      short8 v0 = *(const short8*)(vr + ((hj ^ vxm) << 4));
      zacc[cs] = MFMA32(v0, pf0, zacc[cs]);
      short8 v1 = *(const short8*)(vr + (((2 + hj) ^ vxm) << 4));
      zacc[cs] = MFMA32(v1, pf1, zacc[cs]);
    }
    // ---- P3: PV c-half 1; issue V0[jt+1] ----
    asm volatile("s_waitcnt vmcnt(8)" ::: "memory");
    __builtin_amdgcn_s_barrier();
    stV(jt + 1, 0);
#pragma unroll
    for (int cs = 4; cs < 8; cs++) {
      unsigned char* vr = Vw + 8192 + ((cs - 4) * 32 + l31) * 64;
      short8 v0 = *(const short8*)(vr + ((hj ^ vxm) << 4));
      zacc[cs] = MFMA32(v0, pf0, zacc[cs]);
      short8 v1 = *(const short8*)(vr + (((2 + hj) ^ vxm) << 4));
      zacc[cs] = MFMA32(v1, pf1, zacc[cs]);
    }
  }
  asm volatile("s_waitcnt vmcnt(0)" ::: "memory");
  __builtin_amdgcn_s_barrier();

  // ---- split-K-4 combine ----
  float ls_tot = lsum + __shfl_xor(lsum, 32);
  if (hj == 0) {
    mlb[(wv * 32 + l31) * 2] = mr;
    mlb[(wv * 32 + l31) * 2 + 1] = ls_tot;
  }
  __syncthreads();
  float mj[4], lj[4];
#pragma unroll
  for (int j = 0; j < 4; j++) {
    int widx = j * 2 + qsub;
    mj[j] = mlb[(widx * 32 + l31) * 2];
    lj[j] = mlb[(widx * 32 + l31) * 2 + 1];
  }
  float M = fmaxf(fmaxf(mj[0], mj[1]), fmaxf(mj[2], mj[3]));
  float L = 0.f;
#pragma unroll
  for (int j = 0; j < 4; j++) L += __expf(mj[j] - M) * lj[j];
  float coef = __expf(mr - M) / L;

  float* buf = (kvq >> 1) ? zbufB : zbufA;
  const int qloc = qsub * 32 + l31;
  if (kvq & 1) {
#pragma unroll
    for (int cs = 0; cs < 8; cs++)
#pragma unroll
      for (int r = 0; r < 16; r++) {
        int c = cs * 32 + (r & 3) + 8 * (r >> 2) + 4 * hj;
        buf[qloc * 258 + c] = coef * zacc[cs][r];
      }
  }
  __syncthreads();
  if (!(kvq & 1)) {
#pragma unroll
    for (int cs = 0; cs < 8; cs++)
#pragma unroll
      for (int r = 0; r < 16; r++) {
        int c = cs * 32 + (r & 3) + 8 * (r >> 2) + 4 * hj;
        float* a = &buf[qloc * 258 + c];
        *a = *a + coef * zacc[cs][r];
      }
  }
  __syncthreads();
  {
    int q = tid >> 3, cseg = (tid & 7) * 32;
    const float* A = zbufA + q * 258 + cseg;
    const float* Bq = zbufB + q * 258 + cseg;
    unsigned short* dst = zT + (size_t)(b * N + q0 + q) * C + cseg;
#pragma unroll
    for (int g = 0; g < 4; g++) {
      unsigned int wo[4];
#pragma unroll
      for (int e = 0; e < 4; e++) {
        float lo = A[g * 8 + 2 * e] + Bq[g * 8 + 2 * e];
        float hi = A[g * 8 + 2 * e + 1] + Bq[g * 8 + 2 * e + 1];
        wo[e] = (unsigned int)f2bf(lo) | ((unsigned int)f2bf(hi) << 16);
      }
      u32x4 tw = {wo[0], wo[1], wo[2], wo[3]};
      *(short8*)(dst + g * 8) = __builtin_bit_cast(short8, tw);
    }
  }
}

// ---------------------------------------------------------------------------
// Kernel 2.5: w4 f32 -> bf16
// ---------------------------------------------------------------------------
__global__ __launch_bounds__(256) void w4prep_kernel(
    const float* __restrict__ w4, unsigned short* __restrict__ w4b) {
  int i = (blockIdx.x * 256 + threadIdx.x) * 4;
  f32x4 v = *(const f32x4*)(w4 + i);
  short4v o;
#pragma unroll
  for (int e = 0; e < 4; e++) o[e] = (short)f2bf(v[e]);
  *(short4v*)(w4b + i) = o;
}

// ---------------------------------------------------------------------------
// Kernel 3: y = w4 @ z + b4 -> BN(eval) -> mish -> + rgb. f32 out.
// grid (128,4), block 256.
// ---------------------------------------------------------------------------
__global__ __launch_bounds__(256) void out_kernel(
    const unsigned short* __restrict__ zT, const unsigned short* __restrict__ w4b,
    const float* __restrict__ b4, const float* __restrict__ gamma,
    const float* __restrict__ beta, const float* __restrict__ rmean,
    const float* __restrict__ rvar, const float* __restrict__ rgb,
    float* __restrict__ out) {
  const int tid = threadIdx.x;
  const int b = blockIdx.y;
  const int n0 = blockIdx.x * 32;
  const int wv_ = tid >> 6, lane = tid & 63, l15 = lane & 15, g16 = lane >> 4;
  const f32x4 zero4 = {0.f, 0.f, 0.f, 0.f};

  f32x4 acc[4][2];
#pragma unroll
  for (int i = 0; i < 4; i++)
#pragma unroll
    for (int j = 0; j < 2; j++) acc[i][j] = zero4;

#pragma unroll
  for (int kk = 0; kk < 8; kk++) {
    short8 bfr[2];
#pragma unroll
    for (int nt = 0; nt < 2; nt++)
      bfr[nt] = *(const short8*)(zT + (size_t)(b * N + n0 + nt * 16 + l15) * C +
                                 kk * 32 + 8 * g16);
    short8 afr[4];
#pragma unroll
    for (int mt = 0; mt < 4; mt++)
      afr[mt] = *(const short8*)(w4b + (size_t)(wv_ * 64 + mt * 16 + l15) * C +
                                 kk * 32 + 8 * g16);
#pragma unroll
    for (int mt = 0; mt < 4; mt++)
#pragma unroll
      for (int nt = 0; nt < 2; nt++)
        acc[mt][nt] = MFMA16(afr[mt], bfr[nt], acc[mt][nt]);
  }

#pragma unroll
  for (int mt = 0; mt < 4; mt++)
#pragma unroll
    for (int r = 0; r < 4; r++) {
      int co = wv_ * 64 + mt * 16 + 4 * g16 + r;
      float bb = b4[co];
      float inv = gamma[co] * rsqrtf(rvar[co] + 1e-5f);
      float sh = beta[co] - rmean[co] * inv;
#pragma unroll
      for (int nt = 0; nt < 2; nt++) {
        int n = n0 + nt * 16 + l15;
        size_t idx = (size_t)(b * C + co) * N + n;
        float yv = acc[mt][nt][r] + bb;
        float tv = yv * inv + sh;
        float s = __expf(fminf(tv, 40.f));
        float u = 1.f + s;
        float u2 = u * u;
        float mish = tv * ((u2 - 1.f) / (u2 + 1.f));
        out[idx] = rgb[idx] + mish;
      }
    }
}

// ---------------------------------------------------------------------------
extern "C" void kernel_launch(void* const* d_in, const int* in_sizes, int n_in,
                              void* d_out, int out_size, void* d_ws,
                              size_t ws_size, hipStream_t stream) {
  const float* rgb = (const float*)d_in[0];
  const float* ir = (const float*)d_in[1];
  const float* wq = (const float*)d_in[2];
  const float* bq = (const float*)d_in[3];
  const float* wk = (const float*)d_in[4];
  const float* bk = (const float*)d_in[5];
  const float* wvv = (const float*)d_in[6];
  const float* bvv = (const float*)d_in[7];
  const float* w4 = (const float*)d_in[8];
  const float* b4 = (const float*)d_in[9];
  const float* gamma = (const float*)d_in[10];
  const float* beta = (const float*)d_in[11];
  const float* rmean = (const float*)d_in[12];
  const float* rvar = (const float*)d_in[13];

  unsigned short* qT = (unsigned short*)d_ws;          // [B][N][C] bf16
  unsigned short* kT = qT + (size_t)B * N * C;         // [B][N][C] bf16
  unsigned short* vN = kT + (size_t)B * N * C;         // [B][C][N] bf16
  unsigned short* zT = vN + (size_t)B * N * C;         // [B][N][C] bf16
  unsigned short* w4b = zT + (size_t)B * N * C;        // [C][C] bf16

  w4prep_kernel<<<64, 256, 0, stream>>>(w4, w4b);
  qkv_kernel<<<dim3(16, 16, 3), 256, 0, stream>>>(rgb, ir, wq, bq, wk, bk, wvv,
                                                  bvv, qT, kT, vN);
  attn_kernel<<<256, 512, 0, stream>>>(qT, kT, vN, zT);
  out_kernel<<<dim3(128, 4), 256, 0, stream>>>(zT, w4b, b4, gamma, beta, rmean,
                                               rvar, rgb, (float*)d_out);
}

// Round 7
// 219.005 us; speedup vs baseline: 1.9592x; 1.0049x over previous
//
#include <hip/hip_runtime.h>
#include <stdint.h>
#include <stddef.h>

typedef short short8 __attribute__((ext_vector_type(8)));
typedef short short4v __attribute__((ext_vector_type(4)));
typedef float f32x4 __attribute__((ext_vector_type(4)));
typedef float f32x16 __attribute__((ext_vector_type(16)));
typedef unsigned int u32x4 __attribute__((ext_vector_type(4)));

#define MFMA16(a, b, c) __builtin_amdgcn_mfma_f32_16x16x32_bf16(a, b, c, 0, 0, 0)
#define MFMA32(a, b, c) __builtin_amdgcn_mfma_f32_32x32x16_bf16(a, b, c, 0, 0, 0)
#define P32SWAP(a, b) asm("v_permlane32_swap_b32 %0, %1" : "+v"(a), "+v"(b))

static constexpr int B = 4, C = 256, CG = 64, N = 4096;

__device__ __forceinline__ unsigned short f2bf(float f) {
  unsigned int u = __builtin_bit_cast(unsigned int, f);
  u += 0x7FFFu + ((u >> 16) & 1u);
  return (unsigned short)(u >> 16);
}

__device__ __forceinline__ void async16(const void* g, void* l) {
  __builtin_amdgcn_global_load_lds(
      (const __attribute__((address_space(1))) unsigned int*)g,
      (__attribute__((address_space(3))) unsigned int*)l, 16, 0, 0);
}

// ---------------------------------------------------------------------------
// Kernel 1: grouped 1x1 convs -> qT [b][n][c] (scaled by c^-0.5), kT [b][n][c],
// v [b][c][n], all bf16. grid (16,16,3), block 256. LDS-bounce epilogue for
// coalesced 16B stores.
// ---------------------------------------------------------------------------
__global__ __launch_bounds__(256) void qkv_kernel(
    const float* __restrict__ rgb, const float* __restrict__ ir,
    const float* __restrict__ wq, const float* __restrict__ bq,
    const float* __restrict__ wk, const float* __restrict__ bk,
    const float* __restrict__ wvv, const float* __restrict__ bvv,
    unsigned short* __restrict__ qT, unsigned short* __restrict__ kT,
    unsigned short* __restrict__ vN) {
  __shared__ unsigned char xTs[256 * 144];  // staging + store-bounce reuse
  __shared__ unsigned char wls[64 * 144];

  const int tid = threadIdx.x;
  const int which = blockIdx.z;
  const int bg = blockIdx.y;
  const int b = bg >> 2, g = bg & 3;
  const int n0 = blockIdx.x * 256;

  const float* x = (which == 0) ? rgb : ir;
  const float* w = (which == 0) ? wq : (which == 1 ? wk : wvv);
  const float* bias = (which == 0) ? bq : (which == 1 ? bk : bvv);

  // stage xT: coalesced reads (8 consecutive lanes = 128B contiguous)
  {
    const int p = tid >> 3;           // row-pair 0..31 (cin = 2p, 2p+1)
    const int nlo = (tid & 7) * 4;    // 16B column within 128B segment
    const float* r0 = x + ((size_t)(b * C + g * CG + 2 * p) * N + n0 + nlo);
    const float* r1 = r0 + N;
#pragma unroll
    for (int seg = 0; seg < 8; seg++) {
      f32x4 a = *(const f32x4*)(r0 + seg * 32);
      f32x4 c2 = *(const f32x4*)(r1 + seg * 32);
#pragma unroll
      for (int e = 0; e < 4; e++) {
        unsigned int pk =
            (unsigned int)f2bf(a[e]) | ((unsigned int)f2bf(c2[e]) << 16);
        *(unsigned int*)(xTs + (size_t)(seg * 32 + nlo + e) * 144 + 4 * p) = pk;
      }
    }
  }
  {
    const int o = tid >> 2;
    const int cs = (tid & 3) * 16;
    const float* wr = w + (size_t)g * CG * CG + (size_t)o * CG + cs;
#pragma unroll
    for (int i = 0; i < 8; i++) {
      unsigned int pk = (unsigned int)f2bf(wr[2 * i]) |
                        ((unsigned int)f2bf(wr[2 * i + 1]) << 16);
      *(unsigned int*)(wls + (size_t)o * 144 + (cs + 2 * i) * 2) = pk;
    }
  }
  __syncthreads();

  const int wv_ = tid >> 6, lane = tid & 63, l15 = lane & 15, g16 = lane >> 4;
  const f32x4 zero4 = {0.f, 0.f, 0.f, 0.f};
  f32x4 acc[4][4];
#pragma unroll
  for (int i = 0; i < 4; i++)
#pragma unroll
    for (int j = 0; j < 4; j++) acc[i][j] = zero4;

  if (which < 2) {
#pragma unroll
    for (int kk = 0; kk < 2; kk++) {
      short8 af[4], bfr[4];
#pragma unroll
      for (int mt = 0; mt < 4; mt++)
        af[mt] = *(const short8*)(xTs +
                                  (size_t)(wv_ * 64 + mt * 16 + l15) * 144 +
                                  (kk * 32 + 8 * g16) * 2);
#pragma unroll
      for (int nt = 0; nt < 4; nt++)
        bfr[nt] = *(const short8*)(wls + (size_t)(nt * 16 + l15) * 144 +
                                   (kk * 32 + 8 * g16) * 2);
#pragma unroll
      for (int mt = 0; mt < 4; mt++)
#pragma unroll
        for (int nt = 0; nt < 4; nt++)
          acc[mt][nt] = MFMA16(af[mt], bfr[nt], acc[mt][nt]);
    }
    unsigned short* out = (which == 0) ? qT : kT;
    const float qs = (which == 0) ? 0.0625f : 1.0f;
    __syncthreads();  // xTs reads done; reuse as bounce [n 256][144B]
#pragma unroll
    for (int mt = 0; mt < 4; mt++)
#pragma unroll
      for (int nt = 0; nt < 4; nt++)
#pragma unroll
        for (int r = 0; r < 4; r++) {
          int nl = wv_ * 64 + mt * 16 + 4 * g16 + r;
          int co = nt * 16 + l15;
          float val = (acc[mt][nt][r] + bias[g * CG + co]) * qs;
          *(unsigned short*)(xTs + (size_t)nl * 144 + co * 2) = f2bf(val);
        }
    __syncthreads();
    {
      const int ch = tid & 7;        // 16B chunk in row
      const int rsub = tid >> 3;     // 0..31
#pragma unroll
      for (int ro = 0; ro < 8; ro++) {
        int n = ro * 32 + rsub;
        short8 d = *(const short8*)(xTs + (size_t)n * 144 + ch * 16);
        *(short8*)(out + (size_t)(b * N + n0 + n) * C + g * CG + ch * 8) = d;
      }
    }
  } else {
#pragma unroll
    for (int kk = 0; kk < 2; kk++) {
      short8 af[4], bfr[4];
#pragma unroll
      for (int mt = 0; mt < 4; mt++)
        af[mt] = *(const short8*)(wls + (size_t)(mt * 16 + l15) * 144 +
                                  (kk * 32 + 8 * g16) * 2);
#pragma unroll
      for (int nt = 0; nt < 4; nt++)
        bfr[nt] = *(const short8*)(xTs +
                                   (size_t)(wv_ * 64 + nt * 16 + l15) * 144 +
                                   (kk * 32 + 8 * g16) * 2);
#pragma unroll
      for (int mt = 0; mt < 4; mt++)
#pragma unroll
        for (int nt = 0; nt < 4; nt++)
          acc[mt][nt] = MFMA16(af[mt], bfr[nt], acc[mt][nt]);
    }
    __syncthreads();  // reuse xTs as bounce [co 64][528B]
#pragma unroll
    for (int mt = 0; mt < 4; mt++)
#pragma unroll
      for (int nt = 0; nt < 4; nt++)
#pragma unroll
        for (int r = 0; r < 4; r++) {
          int co = mt * 16 + 4 * g16 + r;
          int nl = wv_ * 64 + nt * 16 + l15;
          float val = acc[mt][nt][r] + bias[g * CG + co];
          *(unsigned short*)(xTs + (size_t)co * 528 + nl * 2) = f2bf(val);
        }
    __syncthreads();
    {
      const int ch = tid & 31;       // 16B chunk in 512B row
      const int rsub = tid >> 5;     // 0..7
#pragma unroll
      for (int ro = 0; ro < 8; ro++) {
        int co = ro * 8 + rsub;
        short8 d = *(const short8*)(xTs + (size_t)co * 528 + ch * 16);
        *(short8*)(vN + (size_t)(b * C + g * CG + co) * N + n0 + ch * 8) = d;
      }
    }
  }
}

// ---------------------------------------------------------------------------
// Kernel 2: flash attention, 32x32 swapped-operand, 2-phase counted-vmcnt
// pipeline + s_setprio around MFMA clusters.
// grid 256 (1 block/CU), block 512 = 4 kv-quarters x 2 q-subtiles.
// Phase A: QK (16 MFMA, full c); prefetch K[jt+1].
// Phase B: softmax + PV (16 MFMA); prefetch V[jt+1]. vmcnt(8) waits only.
// ---------------------------------------------------------------------------
__global__ __launch_bounds__(512, 2) void attn_kernel(
    const unsigned short* __restrict__ qT, const unsigned short* __restrict__ kT,
    const unsigned short* __restrict__ vN, unsigned short* __restrict__ zT) {
  // [0,131072): 4 x (K tile 16KB [half][j32][256B] + V tile 16KB [half][c128][64B])
  // epilogue overlay: zbufA f32[64][258] @0, zbufB @66048, mlbuf @132096
  __shared__ __align__(16) unsigned char smem[134144];

  const int tid = threadIdx.x;
  const int pid = blockIdx.x;  // XCD-chunked swizzle (bijective, 256%8==0)
  const int lg = (pid & 7) * 32 + (pid >> 3);
  const int b = lg >> 6;
  const int q0 = (lg & 63) * 64;
  const int wv = tid >> 6, lane = tid & 63;
  const int l31 = lane & 31, hj = lane >> 5;
  const int qsub = wv & 1, kvq = wv >> 1;

  unsigned char* Kw = smem + kvq * 32768;
  unsigned char* Vw = Kw + 16384;
  float* zbufA = (float*)smem;
  float* zbufB = (float*)(smem + 66048);
  float* mlb = (float*)(smem + 132096);

  // ---- Q fragments (registers, whole kernel) ----
  short8 qf[16];
  {
    const unsigned short* qrow =
        qT + (size_t)(b * N + q0 + qsub * 32 + l31) * C + 8 * hj;
#pragma unroll
    for (int kk = 0; kk < 16; kk++) qf[kk] = *(const short8*)(qrow + 16 * kk);
  }

  f32x16 zacc[8];
#pragma unroll
  for (int cs = 0; cs < 8; cs++)
#pragma unroll
    for (int e = 0; e < 16; e++) zacc[cs][e] = 0.f;
  float mr = 4.0f, lsum = 0.f;

  // ---- staging per-lane geometry ----
  const unsigned short* kq = kT + ((size_t)b * N + kvq * 1024) * C;
  const unsigned short* vq = vN + (size_t)(b * C) * N + kvq * 1024;
  const int t128 = qsub * 64 + lane;  // 0..127 within quarter
  const int r0 = t128 >> 4;           // K row base 0..7
  const int ccp = t128 & 15;          // K physical 16B-chunk in row
  const int cl0 = t128 >> 2;          // V row base 0..31
  const int chl = (t128 & 3) ^ ((cl0 >> 1) & 3);  // V logical chunk

  // K: LDS byte = h*8192 + r*256 + ccp*16 ; src cc_logical = ccp ^ (j&15)
  auto stK = [&](int jt, int h) {
#pragma unroll
    for (int i = 0; i < 4; i++) {
      const unsigned short* src = kq + (size_t)(jt * 32 + i * 8 + r0) * C +
                                  h * 128 + ((ccp ^ r0 ^ ((i & 1) << 3)) << 3);
      async16(src, Kw + h * 8192 + (i * 128 + qsub * 64) * 16);
    }
  };
  // V: LDS byte = h*8192 + c_local*64 + chp*16 ; src chunk = chp ^ ((c>>1)&3)
  auto stV = [&](int jt, int h) {
#pragma unroll
    for (int i = 0; i < 4; i++) {
      const unsigned short* src =
          vq + (size_t)(h * 128 + i * 32 + cl0) * N + jt * 32 + chl * 8;
      async16(src, Vw + h * 8192 + (i * 128 + qsub * 64) * 16);
    }
  };

  // ---- read geometry ----
  const int kxm = l31 & 15;           // K read swizzle mask
  const int vxm = (l31 >> 1) & 3;     // V read swizzle mask
  unsigned char* krow = Kw + l31 * 256;

  // ---- prologue: stage tile 0 (16 loads in flight) ----
  stK(0, 0);
  stK(0, 1);
  stV(0, 0);
  stV(0, 1);

  short8 pf0, pf1;
  for (int jt = 0; jt < 32; jt++) {
    // ---- Phase A: QK over full c; prefetch K[jt+1] ----
    asm volatile("s_waitcnt vmcnt(8)" ::: "memory");  // drain K[jt]
    __builtin_amdgcn_s_barrier();
    stK(jt + 1, 0);
    stK(jt + 1, 1);
    f32x16 s;
#pragma unroll
    for (int e = 0; e < 16; e++) s[e] = 0.f;
    __builtin_amdgcn_s_setprio(1);
#pragma unroll
    for (int kk = 0; kk < 8; kk++) {
      short8 kf = *(const short8*)(krow + (((kk * 2 + hj) ^ kxm) << 4));
      s = MFMA32(kf, qf[kk], s);
    }
#pragma unroll
    for (int kk = 8; kk < 16; kk++) {
      short8 kf = *(const short8*)(krow + 8192 +
                                   ((((kk & 7) * 2 + hj) ^ kxm) << 4));
      s = MFMA32(kf, qf[kk], s);
    }
    __builtin_amdgcn_s_setprio(0);

    // ---- Phase B: softmax + PV; prefetch V[jt+1] ----
    asm volatile("s_waitcnt vmcnt(8)" ::: "memory");  // drain V[jt]
    __builtin_amdgcn_s_barrier();
    stV(jt + 1, 0);
    stV(jt + 1, 1);
    {
      float rmx = s[0];
#pragma unroll
      for (int r = 1; r < 16; r++) rmx = fmaxf(rmx, s[r]);
      rmx = fmaxf(rmx, __shfl_xor(rmx, 32));
      if (__any(rmx > mr + 8.f)) {  // defer-max (rare path)
        float mn = fmaxf(mr, rmx);
        float al = __expf(mr - mn);
        mr = mn;
        lsum *= al;
#pragma unroll
        for (int cs = 0; cs < 8; cs++) zacc[cs] *= al;
      }
      float psum = 0.f;
#pragma unroll
      for (int r = 0; r < 16; r++) {
        s[r] = __expf(s[r] - mr);
        psum += s[r];
      }
      lsum += psum;
      unsigned int w[8];
#pragma unroll
      for (int e = 0; e < 8; e++)
        w[e] = (unsigned int)f2bf(s[2 * e]) |
               ((unsigned int)f2bf(s[2 * e + 1]) << 16);
      P32SWAP(w[0], w[2]);
      P32SWAP(w[1], w[3]);
      P32SWAP(w[4], w[6]);
      P32SWAP(w[5], w[7]);
      u32x4 t0 = {w[0], w[1], w[2], w[3]};
      u32x4 t1 = {w[4], w[5], w[6], w[7]};
      pf0 = __builtin_bit_cast(short8, t0);
      pf1 = __builtin_bit_cast(short8, t1);
    }
    __builtin_amdgcn_s_setprio(1);
#pragma unroll
    for (int cs = 0; cs < 4; cs++) {
      unsigned char* vr = Vw + (cs * 32 + l31) * 64;
      short8 v0 = *(const short8*)(vr + ((hj ^ vxm) << 4));
      zacc[cs] = MFMA32(v0, pf0, zacc[cs]);
      short8 v1 = *(const short8*)(vr + (((2 + hj) ^ vxm) << 4));
      zacc[cs] = MFMA32(v1, pf1, zacc[cs]);
    }
#pragma unroll
    for (int cs = 4; cs < 8; cs++) {
      unsigned char* vr = Vw + 8192 + ((cs - 4) * 32 + l31) * 64;
      short8 v0 = *(const short8*)(vr + ((hj ^ vxm) << 4));
      zacc[cs] = MFMA32(v0, pf0, zacc[cs]);
      short8 v1 = *(const short8*)(vr + (((2 + hj) ^ vxm) << 4));
      zacc[cs] = MFMA32(v1, pf1, zacc[cs]);
    }
    __builtin_amdgcn_s_setprio(0);
  }
  asm volatile("s_waitcnt vmcnt(0)" ::: "memory");
  __builtin_amdgcn_s_barrier();

  // ---- split-K-4 combine ----
  float ls_tot = lsum + __shfl_xor(lsum, 32);
  if (hj == 0) {
    mlb[(wv * 32 + l31) * 2] = mr;
    mlb[(wv * 32 + l31) * 2 + 1] = ls_tot;
  }
  __syncthreads();
  float mj[4], lj[4];
#pragma unroll
  for (int j = 0; j < 4; j++) {
    int widx = j * 2 + qsub;
    mj[j] = mlb[(widx * 32 + l31) * 2];
    lj[j] = mlb[(widx * 32 + l31) * 2 + 1];
  }
  float M = fmaxf(fmaxf(mj[0], mj[1]), fmaxf(mj[2], mj[3]));
  float L = 0.f;
#pragma unroll
  for (int j = 0; j < 4; j++) L += __expf(mj[j] - M) * lj[j];
  float coef = __expf(mr - M) / L;

  float* buf = (kvq >> 1) ? zbufB : zbufA;
  const int qloc = qsub * 32 + l31;
  if (kvq & 1) {
#pragma unroll
    for (int cs = 0; cs < 8; cs++)
#pragma unroll
      for (int r = 0; r < 16; r++) {
        int c = cs * 32 + (r & 3) + 8 * (r >> 2) + 4 * hj;
        buf[qloc * 258 + c] = coef * zacc[cs][r];
      }
  }
  __syncthreads();
  if (!(kvq & 1)) {
#pragma unroll
    for (int cs = 0; cs < 8; cs++)
#pragma unroll
      for (int r = 0; r < 16; r++) {
        int c = cs * 32 + (r & 3) + 8 * (r >> 2) + 4 * hj;
        float* a = &buf[qloc * 258 + c];
        *a = *a + coef * zacc[cs][r];
      }
  }
  __syncthreads();
  {
    int q = tid >> 3, cseg = (tid & 7) * 32;
    const float* A = zbufA + q * 258 + cseg;
    const float* Bq = zbufB + q * 258 + cseg;
    unsigned short* dst = zT + (size_t)(b * N + q0 + q) * C + cseg;
#pragma unroll
    for (int g = 0; g < 4; g++) {
      unsigned int wo[4];
#pragma unroll
      for (int e = 0; e < 4; e++) {
        float lo = A[g * 8 + 2 * e] + Bq[g * 8 + 2 * e];
        float hi = A[g * 8 + 2 * e + 1] + Bq[g * 8 + 2 * e + 1];
        wo[e] = (unsigned int)f2bf(lo) | ((unsigned int)f2bf(hi) << 16);
      }
      u32x4 tw = {wo[0], wo[1], wo[2], wo[3]};
      *(short8*)(dst + g * 8) = __builtin_bit_cast(short8, tw);
    }
  }
}

// ---------------------------------------------------------------------------
// Kernel 2.5: w4 f32 -> bf16
// ---------------------------------------------------------------------------
__global__ __launch_bounds__(256) void w4prep_kernel(
    const float* __restrict__ w4, unsigned short* __restrict__ w4b) {
  int i = (blockIdx.x * 256 + threadIdx.x) * 4;
  f32x4 v = *(const f32x4*)(w4 + i);
  short4v o;
#pragma unroll
  for (int e = 0; e < 4; e++) o[e] = (short)f2bf(v[e]);
  *(short4v*)(w4b + i) = o;
}

// ---------------------------------------------------------------------------
// Kernel 3: y = w4 @ z + b4 -> BN(eval) -> mish -> + rgb. f32 out.
// grid (128,4), block 256. LDS-bounce epilogue for f32x4 coalesced I/O.
// ---------------------------------------------------------------------------
__global__ __launch_bounds__(256) void out_kernel(
    const unsigned short* __restrict__ zT, const unsigned short* __restrict__ w4b,
    const float* __restrict__ b4, const float* __restrict__ gamma,
    const float* __restrict__ beta, const float* __restrict__ rmean,
    const float* __restrict__ rvar, const float* __restrict__ rgb,
    float* __restrict__ out) {
  __shared__ float yb[256 * 36];   // [co 256][n 32 pad->36] f32
  __shared__ float invs[256], shbs[256];

  const int tid = threadIdx.x;
  const int b = blockIdx.y;
  const int n0 = blockIdx.x * 32;
  const int wv_ = tid >> 6, lane = tid & 63, l15 = lane & 15, g16 = lane >> 4;
  const f32x4 zero4 = {0.f, 0.f, 0.f, 0.f};

  {
    int co = tid;
    float inv = gamma[co] * rsqrtf(rvar[co] + 1e-5f);
    invs[co] = inv;
    shbs[co] = b4[co] * inv + beta[co] - rmean[co] * inv;
  }

  f32x4 acc[4][2];
#pragma unroll
  for (int i = 0; i < 4; i++)
#pragma unroll
    for (int j = 0; j < 2; j++) acc[i][j] = zero4;

#pragma unroll
  for (int kk = 0; kk < 8; kk++) {
    short8 bfr[2];
#pragma unroll
    for (int nt = 0; nt < 2; nt++)
      bfr[nt] = *(const short8*)(zT + (size_t)(b * N + n0 + nt * 16 + l15) * C +
                                 kk * 32 + 8 * g16);
    short8 afr[4];
#pragma unroll
    for (int mt = 0; mt < 4; mt++)
      afr[mt] = *(const short8*)(w4b + (size_t)(wv_ * 64 + mt * 16 + l15) * C +
                                 kk * 32 + 8 * g16);
#pragma unroll
    for (int mt = 0; mt < 4; mt++)
#pragma unroll
      for (int nt = 0; nt < 2; nt++)
        acc[mt][nt] = MFMA16(afr[mt], bfr[nt], acc[mt][nt]);
  }

#pragma unroll
  for (int mt = 0; mt < 4; mt++)
#pragma unroll
    for (int r = 0; r < 4; r++) {
      int co = wv_ * 64 + mt * 16 + 4 * g16 + r;
#pragma unroll
      for (int nt = 0; nt < 2; nt++)
        yb[co * 36 + nt * 16 + l15] = acc[mt][nt][r];
    }
  __syncthreads();
  {
    const int ch = tid & 7;      // f32x4 chunk in 32-n row
    const int rsub = tid >> 3;   // 0..31
#pragma unroll
    for (int ro = 0; ro < 8; ro++) {
      int co = ro * 32 + rsub;
      float inv = invs[co], shb = shbs[co];
      f32x4 yv = *(const f32x4*)(yb + co * 36 + ch * 4);
      size_t idx = (size_t)(b * C + co) * N + n0 + ch * 4;
      f32x4 rg = *(const f32x4*)(rgb + idx);
      f32x4 o;
#pragma unroll
      for (int e = 0; e < 4; e++) {
        float tv = yv[e] * inv + shb;
        float s = __expf(fminf(tv, 40.f));
        float u = 1.f + s;
        float u2 = u * u;
        o[e] = rg[e] + tv * ((u2 - 1.f) / (u2 + 1.f));
      }
      *(f32x4*)(out + idx) = o;
    }
  }
}

// ---------------------------------------------------------------------------
extern "C" void kernel_launch(void* const* d_in, const int* in_sizes, int n_in,
                              void* d_out, int out_size, void* d_ws,
                              size_t ws_size, hipStream_t stream) {
  const float* rgb = (const float*)d_in[0];
  const float* ir = (const float*)d_in[1];
  const float* wq = (const float*)d_in[2];
  const float* bq = (const float*)d_in[3];
  const float* wk = (const float*)d_in[4];
  const float* bk = (const float*)d_in[5];
  const float* wvv = (const float*)d_in[6];
  const float* bvv = (const float*)d_in[7];
  const float* w4 = (const float*)d_in[8];
  const float* b4 = (const float*)d_in[9];
  const float* gamma = (const float*)d_in[10];
  const float* beta = (const float*)d_in[11];
  const float* rmean = (const float*)d_in[12];
  const float* rvar = (const float*)d_in[13];

  unsigned short* qT = (unsigned short*)d_ws;          // [B][N][C] bf16
  unsigned short* kT = qT + (size_t)B * N * C;         // [B][N][C] bf16
  unsigned short* vN = kT + (size_t)B * N * C;         // [B][C][N] bf16
  unsigned short* zT = vN + (size_t)B * N * C;         // [B][N][C] bf16
  unsigned short* w4b = zT + (size_t)B * N * C;        // [C][C] bf16

  w4prep_kernel<<<64, 256, 0, stream>>>(w4, w4b);
  qkv_kernel<<<dim3(16, 16, 3), 256, 0, stream>>>(rgb, ir, wq, bq, wk, bk, wvv,
                                                  bvv, qT, kT, vN);
  attn_kernel<<<256, 512, 0, stream>>>(qT, kT, vN, zT);
  out_kernel<<<dim3(128, 4), 256, 0, stream>>>(zT, w4b, b4, gamma, beta, rmean,
                                               rvar, rgb, (float*)d_out);
}